// Round 1
// baseline (17527.927 us; speedup 1.0000x reference)
//
#include <hip/hip_runtime.h>
#include <math.h>

// ---------------- dims ----------------
#define B_ 8
#define T_ 4
#define C_ 12
#define H_ 128
#define W_ 256
#define P_ 128
#define S_ 512
#define D_ 768
#define NH_ 12
#define HD_ 64
#define L_ 8
#define MLP_ 3072
#define DD_ 512
#define NHD_ 8
#define LD_ 4
#define MLPD_ 2048
#define OUT_ 768

// ---------------- small utility kernels ----------------

__global__ void mask_k(const float* __restrict__ mr, int* __restrict__ blocked) {
    int i = threadIdx.x; // 128 = L*T*T
    if (i < L_ * T_ * T_) {
        int tk = i & 3, tq = (i >> 2) & 3;
        blocked[i] = (mr[i] < 0.8f && tk > tq) ? 1 : 0;
    }
}

// wkT[k][n] = conv_w[n][k],  k<3072, n<768. Each thread does 4 k's for one n.
__global__ void transpose_k(const float* __restrict__ cw, float* __restrict__ wkT) {
    int tid = blockIdx.x * 256 + threadIdx.x; // 589824 threads
    if (tid >= (3072 / 4) * 768) return;
    int n = tid % 768;
    int k0 = (tid / 768) * 4;
    float4 v = *(const float4*)(cw + (size_t)n * 3072 + k0);
    wkT[(size_t)(k0 + 0) * 768 + n] = v.x;
    wkT[(size_t)(k0 + 1) * 768 + n] = v.y;
    wkT[(size_t)(k0 + 2) * 768 + n] = v.z;
    wkT[(size_t)(k0 + 3) * 768 + n] = v.w;
}

// xf[bt, p, c*256+ph*16+pw] = x[bt, c, hp*16+ph, wp*16+pw]
__global__ void gather_k(const float* __restrict__ x, float* __restrict__ xf) {
    size_t i4 = ((size_t)blockIdx.x * 256 + threadIdx.x) * 4;
    if (i4 >= (size_t)4096 * 3072) return;
    int row = (int)(i4 / 3072), col = (int)(i4 % 3072);
    int bt = row >> 7, p = row & 127;
    int hp = p >> 4, wp = p & 15;
    int c = col >> 8, rem = col & 255;
    int ph = rem >> 4, pw0 = rem & 15; // multiple of 4
    const float* src = x + (((size_t)(bt * C_ + c) * H_ + hp * 16 + ph) * W_ + wp * 16 + pw0);
    *(float4*)(xf + i4) = *(const float4*)src;
}

// h[r][n] += pos_emb[r%512][n]
__global__ void addpos_k(float* __restrict__ h, const float* __restrict__ pos) {
    size_t i4 = ((size_t)blockIdx.x * 256 + threadIdx.x) * 4;
    if (i4 >= (size_t)4096 * 768) return;
    int r = (int)(i4 / 768), n = (int)(i4 % 768);
    int s = r & 511;
    float4 a = *(float4*)(h + i4);
    float4 b = *(const float4*)(pos + (size_t)s * 768 + n);
    a.x += b.x; a.y += b.y; a.z += b.z; a.w += b.w;
    *(float4*)(h + i4) = a;
}

// dq[(b*128+p)*512+c] = dec_query[p*512+c]
__global__ void dqinit_k(float* __restrict__ dq, const float* __restrict__ q0) {
    size_t i4 = ((size_t)blockIdx.x * 256 + threadIdx.x) * 4;
    if (i4 >= (size_t)1024 * 512) return;
    int row = (int)(i4 / 512), col = (int)(i4 % 512);
    int p = row & 127;
    *(float4*)(dq + i4) = *(const float4*)(q0 + (size_t)p * 512 + col);
}

// ---------------- layernorm ----------------
__global__ __launch_bounds__(256) void ln_k(const float* __restrict__ X, float* __restrict__ Y,
                                            const float* __restrict__ sc, const float* __restrict__ bi,
                                            int cols) {
    int row = blockIdx.x;
    int t = threadIdx.x;
    const float* x = X + (size_t)row * cols;
    float s = 0.f, sq = 0.f;
    for (int c = t; c < cols; c += 256) { float v = x[c]; s += v; sq += v * v; }
    for (int o = 32; o; o >>= 1) { s += __shfl_xor(s, o); sq += __shfl_xor(sq, o); }
    __shared__ float rs[4], rq[4];
    if ((t & 63) == 0) { rs[t >> 6] = s; rq[t >> 6] = sq; }
    __syncthreads();
    s = rs[0] + rs[1] + rs[2] + rs[3];
    sq = rq[0] + rq[1] + rq[2] + rq[3];
    float mean = s / cols;
    float var = sq / cols - mean * mean;
    float inv = rsqrtf(var + 1e-5f);
    float* y = Y + (size_t)row * cols;
    for (int c = t; c < cols; c += 256) {
        float v = (x[c] - mean) * inv;
        y[c] = v * sc[c] + bi[c];
    }
}

// ---------------- generic fp32 GEMM: C = epi(A@B + bias) (+res) ----------------
// A: MxK row-major, B: KxN row-major. M%128==0, N%128==0, K%8==0.
__global__ __launch_bounds__(256) void gemm_k(const float* __restrict__ A, const float* __restrict__ Bm,
                                              const float* __restrict__ bias, const float* __restrict__ res,
                                              float* __restrict__ Cm, int M, int N, int K, int dogelu) {
    __shared__ float As[8][132];
    __shared__ float Bs[8][132];
    const int t = threadIdx.x;
    const int bn = blockIdx.x, bm = blockIdx.y;
    const int tx = t & 15, ty = t >> 4;
    const int row0 = bm * 128, col0 = bn * 128;
    float acc[8][8];
#pragma unroll
    for (int i = 0; i < 8; ++i)
#pragma unroll
        for (int j = 0; j < 8; ++j) acc[i][j] = 0.f;

    const int arow = t >> 1, acol = (t & 1) * 4;
    const int brow = t >> 5, bcol = (t & 31) * 4;
    const float* Aptr = A + (size_t)(row0 + arow) * K + acol;
    const float* Bptr = Bm + (size_t)brow * N + col0 + bcol;

    for (int k0 = 0; k0 < K; k0 += 8) {
        float4 av = *(const float4*)(Aptr + k0);
        float4 bv = *(const float4*)(Bptr + (size_t)k0 * N);
        __syncthreads();
        As[acol + 0][arow] = av.x;
        As[acol + 1][arow] = av.y;
        As[acol + 2][arow] = av.z;
        As[acol + 3][arow] = av.w;
        *(float4*)&Bs[brow][bcol] = bv;
        __syncthreads();
#pragma unroll
        for (int kk = 0; kk < 8; ++kk) {
            float4 a0 = *(const float4*)&As[kk][ty * 8];
            float4 a1 = *(const float4*)&As[kk][ty * 8 + 4];
            float4 b0 = *(const float4*)&Bs[kk][tx * 8];
            float4 b1 = *(const float4*)&Bs[kk][tx * 8 + 4];
            float a[8] = {a0.x, a0.y, a0.z, a0.w, a1.x, a1.y, a1.z, a1.w};
            float b[8] = {b0.x, b0.y, b0.z, b0.w, b1.x, b1.y, b1.z, b1.w};
#pragma unroll
            for (int i = 0; i < 8; ++i)
#pragma unroll
                for (int j = 0; j < 8; ++j) acc[i][j] += a[i] * b[j];
        }
    }
#pragma unroll
    for (int i = 0; i < 8; ++i) {
        int r = row0 + ty * 8 + i;
#pragma unroll
        for (int j = 0; j < 8; ++j) {
            int c = col0 + tx * 8 + j;
            float v = acc[i][j];
            if (bias) v += bias[c];
            if (dogelu) v = 0.5f * v * (1.0f + erff(v * 0.70710678118654752f));
            if (res) v += res[(size_t)r * N + c];
            Cm[(size_t)r * N + c] = v;
        }
    }
}

// ---------------- attention: scores + softmax -> P ----------------
// Block: 16 q-rows for one (b,h). P layout: [(lb*nh+h)*Sq + q][Sk]
__global__ __launch_bounds__(256) void attn_score_k(const float* __restrict__ Qp, const float* __restrict__ Kp,
                                                    float* __restrict__ Pp,
                                                    int q_rstride, int k_rstride, int Sq, int Sk, int nh,
                                                    float scale, const int* __restrict__ blk, int b0) {
    __shared__ float qt[16][68];
    __shared__ float kt[64][68];
    __shared__ float sc[16][516];
    const int t = threadIdx.x;
    const int bh = blockIdx.x;
    const int lb = bh / nh, hh = bh % nh;
    const int b = b0 + lb;
    const int q0 = blockIdx.y * 16;
    const int tq = q0 >> 7;

    { // stage 16x64 q tile
        int r = t >> 4, c = (t & 15) * 4;
        const float* src = Qp + (size_t)(b * Sq + q0 + r) * q_rstride + hh * 64 + c;
        *(float4*)&qt[r][c] = *(const float4*)src;
    }

    const int ql = t & 15, kg = t >> 4;
    for (int kc = 0; kc < Sk; kc += 64) {
        bool skip = false;
        if (blk) skip = blk[tq * 4 + (kc >> 7)] != 0;
        if (skip) continue;
        __syncthreads();
        { // stage 64x64 K chunk
            int r = t >> 2, c0 = (t & 3) * 16;
            const float* src = Kp + (size_t)(b * Sk + kc + r) * k_rstride + hh * 64 + c0;
#pragma unroll
            for (int u = 0; u < 4; ++u)
                *(float4*)&kt[r][c0 + u * 4] = *(const float4*)(src + u * 4);
        }
        __syncthreads();
        float s0 = 0.f, s1 = 0.f, s2 = 0.f, s3 = 0.f;
#pragma unroll
        for (int d = 0; d < 64; d += 4) {
            float4 qv = *(const float4*)&qt[ql][d];
            float4 k0v = *(const float4*)&kt[kg * 4 + 0][d];
            float4 k1v = *(const float4*)&kt[kg * 4 + 1][d];
            float4 k2v = *(const float4*)&kt[kg * 4 + 2][d];
            float4 k3v = *(const float4*)&kt[kg * 4 + 3][d];
            s0 += qv.x * k0v.x + qv.y * k0v.y + qv.z * k0v.z + qv.w * k0v.w;
            s1 += qv.x * k1v.x + qv.y * k1v.y + qv.z * k1v.z + qv.w * k1v.w;
            s2 += qv.x * k2v.x + qv.y * k2v.y + qv.z * k2v.z + qv.w * k2v.w;
            s3 += qv.x * k3v.x + qv.y * k3v.y + qv.z * k3v.z + qv.w * k3v.w;
        }
        sc[ql][kc + kg * 4 + 0] = s0 * scale;
        sc[ql][kc + kg * 4 + 1] = s1 * scale;
        sc[ql][kc + kg * 4 + 2] = s2 * scale;
        sc[ql][kc + kg * 4 + 3] = s3 * scale;
    }
    __syncthreads();

    // softmax over Sk (chunks of 64 lanes-wide), rows split across 4 waves
    const int wave = t >> 6, lane = t & 63;
    const int nchunk = Sk >> 6;
    for (int r = wave; r < 16; r += 4) {
        float vals[8];
        float m = -1e30f;
        for (int i = 0; i < nchunk; ++i) {
            bool ok = true;
            if (blk) ok = blk[tq * 4 + ((i * 64) >> 7)] == 0;
            vals[i] = ok ? sc[r][i * 64 + lane] : -1e30f;
            m = fmaxf(m, vals[i]);
        }
        for (int o = 32; o; o >>= 1) m = fmaxf(m, __shfl_xor(m, o));
        float ssum = 0.f;
        for (int i = 0; i < nchunk; ++i) {
            float e = (vals[i] > -1e29f) ? __expf(vals[i] - m) : 0.f;
            vals[i] = e;
            ssum += e;
        }
        for (int o = 32; o; o >>= 1) ssum += __shfl_xor(ssum, o);
        float inv = 1.f / ssum;
        float* pr = Pp + ((size_t)(lb * nh + hh) * Sq + q0 + r) * Sk;
        for (int i = 0; i < nchunk; ++i) pr[i * 64 + lane] = vals[i] * inv;
    }
}

// ---------------- attention: O = P @ V ----------------
// Block: 4 q-rows x 64 dims for one (b,h); V chunk staged in LDS.
__global__ __launch_bounds__(256) void attn_pv_k(const float* __restrict__ Pp, const float* __restrict__ Vp,
                                                 float* __restrict__ Op,
                                                 int v_rstride, int o_rstride, int Sq, int Sk, int nh,
                                                 const int* __restrict__ blk, int b0) {
    __shared__ float Vs[128][68];
    const int t = threadIdx.x;
    const int bh = blockIdx.x;
    const int lb = bh / nh, hh = bh % nh;
    const int b = b0 + lb;
    const int q0 = blockIdx.y * 4;
    const int ql = t >> 6, d = t & 63;
    const int q = q0 + ql;
    const int tq = q >> 7;
    const float* prow = Pp + ((size_t)(lb * nh + hh) * Sq + q) * Sk;
    float acc = 0.f;
    for (int kc = 0; kc < Sk; kc += 128) {
        bool skip = false;
        if (blk) skip = blk[tq * 4 + (kc >> 7)] != 0;
        if (skip) continue;
        __syncthreads();
#pragma unroll
        for (int u = 0; u < 8; ++u) {
            int idx = t + u * 256;
            int r = idx >> 4, c = (idx & 15) * 4;
            const float* src = Vp + (size_t)(b * Sk + kc + r) * v_rstride + hh * 64 + c;
            *(float4*)&Vs[r][c] = *(const float4*)src;
        }
        __syncthreads();
#pragma unroll 4
        for (int j = 0; j < 128; ++j) acc += prow[kc + j] * Vs[j][d];
    }
    Op[(size_t)(b * Sq + q) * o_rstride + hh * 64 + d] = acc;
}

// ---------------- host ----------------
extern "C" void kernel_launch(void* const* d_in, const int* in_sizes, int n_in,
                              void* d_out, int out_size, void* d_ws, size_t ws_size,
                              hipStream_t stream) {
    (void)in_sizes; (void)n_in; (void)out_size;
    const float* x          = (const float*)d_in[0];
    const float* mask_rand  = (const float*)d_in[1];
    const float* conv_w     = (const float*)d_in[2];
    const float* conv_b     = (const float*)d_in[3];
    const float* pos_emb    = (const float*)d_in[4];
    const float* enc_ln1_s  = (const float*)d_in[5];
    const float* enc_ln1_b  = (const float*)d_in[6];
    const float* enc_qkv_w  = (const float*)d_in[7];
    const float* enc_proj_w = (const float*)d_in[8];
    const float* enc_proj_b = (const float*)d_in[9];
    const float* enc_ln2_s  = (const float*)d_in[10];
    const float* enc_ln2_b  = (const float*)d_in[11];
    const float* enc_mlp_w1 = (const float*)d_in[12];
    const float* enc_mlp_b1 = (const float*)d_in[13];
    const float* enc_mlp_w2 = (const float*)d_in[14];
    const float* enc_mlp_b2 = (const float*)d_in[15];
    const float* e2d_w      = (const float*)d_in[16];
    const float* e2d_b      = (const float*)d_in[17];
    const float* dec_query  = (const float*)d_in[18];
    const float* dec_ln1_s  = (const float*)d_in[19];
    const float* dec_ln1_b  = (const float*)d_in[20];
    const float* dec_qkv_w  = (const float*)d_in[21];
    const float* dec_qkv_b  = (const float*)d_in[22];
    const float* dec_out_w  = (const float*)d_in[23];
    const float* dec_out_b  = (const float*)d_in[24];
    const float* dec_ln2_s  = (const float*)d_in[25];
    const float* dec_ln2_b  = (const float*)d_in[26];
    const float* dec_mlp_w1 = (const float*)d_in[27];
    const float* dec_mlp_b1 = (const float*)d_in[28];
    const float* dec_mlp_w2 = (const float*)d_in[29];
    const float* dec_mlp_b2 = (const float*)d_in[30];
    const float* head_ln_s  = (const float*)d_in[31];
    const float* head_ln_b  = (const float*)d_in[32];
    const float* head_w     = (const float*)d_in[33];
    const float* head_b     = (const float*)d_in[34];
    float* outp = (float*)d_out;

    // workspace layout (floats)
    float* w = (float*)d_ws;
    size_t off = 0;
    int* blockedp = (int*)w; off += 128;
    float* h_buf   = w + off; off += (size_t)4096 * 768;
    float* y_buf   = w + off; off += (size_t)4096 * 768;   // also attn-O buffer
    float* qkv_buf = w + off; off += (size_t)4096 * 2304;  // also wkT, also dec Q/K/V
    float* mlp_buf = w + off; off += (size_t)4096 * 3072;  // also xf, also dec mlp
    float* mem_buf = w + off; off += (size_t)4096 * 512;
    float* dq_buf  = w + off; off += (size_t)1024 * 512;
    float* p_buf   = w + off;
    size_t avail = (ws_size / 4 > off) ? (ws_size / 4 - off) : 0;
    int NBe = 8;
    while (NBe > 1 && (size_t)NBe * NH_ * S_ * S_ > avail) NBe >>= 1;
    int NBd = 8;
    while (NBd > 1 && (size_t)NBd * NHD_ * P_ * S_ > avail) NBd >>= 1;

    float* wkT = qkv_buf;
    float* xf  = mlp_buf;

    const float scale = 0.125f; // HD^-0.5 == HDD^-0.5

    // 0) mask
    hipLaunchKernelGGL(mask_k, dim3(1), dim3(128), 0, stream, mask_rand, blockedp);
    // 1) wkT = conv_w^T
    hipLaunchKernelGGL(transpose_k, dim3(2304), dim3(256), 0, stream, conv_w, wkT);
    // 2) gather xf
    hipLaunchKernelGGL(gather_k, dim3(12288), dim3(256), 0, stream, x, xf);
    // 3) tok = xf @ wkT + conv_b  -> h
    hipLaunchKernelGGL(gemm_k, dim3(768 / 128, 4096 / 128), dim3(256), 0, stream,
                       xf, wkT, conv_b, (const float*)nullptr, h_buf, 4096, 768, 3072, 0);
    // 4) + pos_emb
    hipLaunchKernelGGL(addpos_k, dim3(3072), dim3(256), 0, stream, h_buf, pos_emb);

    // -------- encoder --------
    for (int l = 0; l < L_; ++l) {
        const int* blk = blockedp + l * 16;
        hipLaunchKernelGGL(ln_k, dim3(4096), dim3(256), 0, stream,
                           h_buf, y_buf, enc_ln1_s + l * 768, enc_ln1_b + l * 768, 768);
        hipLaunchKernelGGL(gemm_k, dim3(2304 / 128, 4096 / 128), dim3(256), 0, stream,
                           y_buf, enc_qkv_w + (size_t)l * 768 * 2304, (const float*)nullptr,
                           (const float*)nullptr, qkv_buf, 4096, 2304, 768, 0);
        for (int b0 = 0; b0 < B_; b0 += NBe) {
            int nb = (B_ - b0 < NBe) ? (B_ - b0) : NBe;
            hipLaunchKernelGGL(attn_score_k, dim3(NH_ * nb, S_ / 16), dim3(256), 0, stream,
                               qkv_buf, qkv_buf + 768, p_buf, 2304, 2304, S_, S_, NH_, scale, blk, b0);
            hipLaunchKernelGGL(attn_pv_k, dim3(NH_ * nb, S_ / 4), dim3(256), 0, stream,
                               p_buf, qkv_buf + 1536, y_buf, 2304, 768, S_, S_, NH_, blk, b0);
        }
        hipLaunchKernelGGL(gemm_k, dim3(768 / 128, 4096 / 128), dim3(256), 0, stream,
                           y_buf, enc_proj_w + (size_t)l * 768 * 768, enc_proj_b + l * 768,
                           h_buf, h_buf, 4096, 768, 768, 0);
        hipLaunchKernelGGL(ln_k, dim3(4096), dim3(256), 0, stream,
                           h_buf, y_buf, enc_ln2_s + l * 768, enc_ln2_b + l * 768, 768);
        hipLaunchKernelGGL(gemm_k, dim3(3072 / 128, 4096 / 128), dim3(256), 0, stream,
                           y_buf, enc_mlp_w1 + (size_t)l * 768 * 3072, enc_mlp_b1 + l * 3072,
                           (const float*)nullptr, mlp_buf, 4096, 3072, 768, 1);
        hipLaunchKernelGGL(gemm_k, dim3(768 / 128, 4096 / 128), dim3(256), 0, stream,
                           mlp_buf, enc_mlp_w2 + (size_t)l * 3072 * 768, enc_mlp_b2 + l * 768,
                           h_buf, h_buf, 4096, 768, 3072, 0);
    }

    // -------- enc2dec --------
    hipLaunchKernelGGL(gemm_k, dim3(512 / 128, 4096 / 128), dim3(256), 0, stream,
                       h_buf, e2d_w, e2d_b, (const float*)nullptr, mem_buf, 4096, 512, 768, 0);
    hipLaunchKernelGGL(dqinit_k, dim3(512), dim3(256), 0, stream, dq_buf, dec_query);

    // -------- decoder --------
    float* Qd = qkv_buf;
    float* Kd = qkv_buf + (size_t)1024 * 512;
    float* Vd = Kd + (size_t)4096 * 512;
    for (int l = 0; l < LD_; ++l) {
        hipLaunchKernelGGL(ln_k, dim3(1024), dim3(256), 0, stream,
                           dq_buf, y_buf, dec_ln1_s + l * 512, dec_ln1_b + l * 512, 512);
        hipLaunchKernelGGL(gemm_k, dim3(512 / 128, 1024 / 128), dim3(256), 0, stream,
                           y_buf, dec_qkv_w + ((size_t)l * 3 + 0) * 512 * 512, dec_qkv_b + (l * 3 + 0) * 512,
                           (const float*)nullptr, Qd, 1024, 512, 512, 0);
        hipLaunchKernelGGL(gemm_k, dim3(512 / 128, 4096 / 128), dim3(256), 0, stream,
                           mem_buf, dec_qkv_w + ((size_t)l * 3 + 1) * 512 * 512, dec_qkv_b + (l * 3 + 1) * 512,
                           (const float*)nullptr, Kd, 4096, 512, 512, 0);
        hipLaunchKernelGGL(gemm_k, dim3(512 / 128, 4096 / 128), dim3(256), 0, stream,
                           mem_buf, dec_qkv_w + ((size_t)l * 3 + 2) * 512 * 512, dec_qkv_b + (l * 3 + 2) * 512,
                           (const float*)nullptr, Vd, 4096, 512, 512, 0);
        for (int b0 = 0; b0 < B_; b0 += NBd) {
            int nb = (B_ - b0 < NBd) ? (B_ - b0) : NBd;
            hipLaunchKernelGGL(attn_score_k, dim3(NHD_ * nb, P_ / 16), dim3(256), 0, stream,
                               Qd, Kd, p_buf, 512, 512, P_, S_, NHD_, scale, (const int*)nullptr, b0);
            hipLaunchKernelGGL(attn_pv_k, dim3(NHD_ * nb, P_ / 4), dim3(256), 0, stream,
                               p_buf, Vd, y_buf, 512, 512, P_, S_, NHD_, (const int*)nullptr, b0);
        }
        hipLaunchKernelGGL(gemm_k, dim3(512 / 128, 1024 / 128), dim3(256), 0, stream,
                           y_buf, dec_out_w + (size_t)l * 512 * 512, dec_out_b + l * 512,
                           dq_buf, dq_buf, 1024, 512, 512, 0);
        hipLaunchKernelGGL(ln_k, dim3(1024), dim3(256), 0, stream,
                           dq_buf, y_buf, dec_ln2_s + l * 512, dec_ln2_b + l * 512, 512);
        hipLaunchKernelGGL(gemm_k, dim3(2048 / 128, 1024 / 128), dim3(256), 0, stream,
                           y_buf, dec_mlp_w1 + (size_t)l * 512 * 2048, dec_mlp_b1 + l * 2048,
                           (const float*)nullptr, mlp_buf, 1024, 2048, 512, 1);
        hipLaunchKernelGGL(gemm_k, dim3(512 / 128, 1024 / 128), dim3(256), 0, stream,
                           mlp_buf, dec_mlp_w2 + (size_t)l * 2048 * 512, dec_mlp_b2 + l * 512,
                           dq_buf, dq_buf, 1024, 512, 2048, 0);
    }

    // -------- head --------
    hipLaunchKernelGGL(ln_k, dim3(1024), dim3(256), 0, stream,
                       dq_buf, y_buf, head_ln_s, head_ln_b, 512);
    hipLaunchKernelGGL(gemm_k, dim3(768 / 128, 1024 / 128), dim3(256), 0, stream,
                       y_buf, head_w, head_b, (const float*)nullptr, outp, 1024, 768, 512, 0);
}

// Round 2
// 6726.839 us; speedup vs baseline: 2.6057x; 2.6057x over previous
//
#include <hip/hip_runtime.h>
#include <math.h>

// ---------------- dims ----------------
#define B_ 8
#define T_ 4
#define C_ 12
#define H_ 128
#define W_ 256
#define P_ 128
#define S_ 512
#define D_ 768
#define NH_ 12
#define HD_ 64
#define L_ 8
#define MLP_ 3072
#define DD_ 512
#define NHD_ 8
#define LD_ 4
#define MLPD_ 2048
#define OUT_ 768

typedef __bf16 bf16x8 __attribute__((ext_vector_type(8)));
typedef float f32x4 __attribute__((ext_vector_type(4)));

static __device__ __forceinline__ unsigned short f2bf(float f) {
    unsigned int u = __float_as_uint(f);
    unsigned int r = (u + 0x7fffu + ((u >> 16) & 1u)) >> 16;
    return (unsigned short)r;
}

#define GLDS(gp, lp) __builtin_amdgcn_global_load_lds( \
    (const __attribute__((address_space(1))) void*)(gp), \
    (__attribute__((address_space(3))) void*)(lp), 16, 0, 0)

// ---------------- small utility kernels ----------------

__global__ void mask_k(const float* __restrict__ mr, int* __restrict__ blocked) {
    int i = threadIdx.x; // 128 = L*T*T
    if (i < L_ * T_ * T_) {
        int tk = i & 3, tq = (i >> 2) & 3;
        blocked[i] = (mr[i] < 0.8f && tk > tq) ? 1 : 0;
    }
}

// batched transpose + cast: in (batch, Kd, Nd) fp32 -> out (batch, Nd, Kd) bf16
__global__ __launch_bounds__(256) void wtrans_k(const float* __restrict__ in, unsigned short* __restrict__ out,
                                                int Kd, int Nd) {
    __shared__ float tile[32][33];
    int n0 = blockIdx.x * 32, k0 = blockIdx.y * 32;
    size_t boff = (size_t)blockIdx.z * Kd * Nd;
    const float* src = in + boff;
    unsigned short* dst = out + boff;
    int tx = threadIdx.x & 31, ty = threadIdx.x >> 5; // 32 x 8
#pragma unroll
    for (int i = 0; i < 32; i += 8)
        tile[ty + i][tx] = src[(size_t)(k0 + ty + i) * Nd + n0 + tx];
    __syncthreads();
#pragma unroll
    for (int i = 0; i < 32; i += 8)
        dst[(size_t)(n0 + ty + i) * Kd + k0 + tx] = f2bf(tile[tx][ty + i]);
}

// linear cast fp32 -> bf16, n multiple of 4
__global__ void cast_k(const float* __restrict__ in, unsigned short* __restrict__ out, int n4) {
    int i = blockIdx.x * 256 + threadIdx.x;
    if (i >= n4) return;
    float4 v = *(const float4*)(in + (size_t)i * 4);
    uint2 o;
    o.x = (unsigned)f2bf(v.x) | ((unsigned)f2bf(v.y) << 16);
    o.y = (unsigned)f2bf(v.z) | ((unsigned)f2bf(v.w) << 16);
    *(uint2*)(out + (size_t)i * 4) = o;
}

// xf[bt, p, c*256+ph*16+pw] = x[bt, c, hp*16+ph, wp*16+pw]  (bf16 out)
__global__ void gather_k(const float* __restrict__ x, unsigned short* __restrict__ xf) {
    size_t i4 = ((size_t)blockIdx.x * 256 + threadIdx.x) * 4;
    if (i4 >= (size_t)4096 * 3072) return;
    int row = (int)(i4 / 3072), col = (int)(i4 % 3072);
    int bt = row >> 7, p = row & 127;
    int hp = p >> 4, wp = p & 15;
    int c = col >> 8, rem = col & 255;
    int ph = rem >> 4, pw0 = rem & 15; // multiple of 4
    const float* src = x + (((size_t)(bt * C_ + c) * H_ + hp * 16 + ph) * W_ + wp * 16 + pw0);
    float4 v = *(const float4*)src;
    uint2 o;
    o.x = (unsigned)f2bf(v.x) | ((unsigned)f2bf(v.y) << 16);
    o.y = (unsigned)f2bf(v.z) | ((unsigned)f2bf(v.w) << 16);
    *(uint2*)(xf + i4) = o;
}

// h[r][n] += pos_emb[r%512][n]
__global__ void addpos_k(float* __restrict__ h, const float* __restrict__ pos) {
    size_t i4 = ((size_t)blockIdx.x * 256 + threadIdx.x) * 4;
    if (i4 >= (size_t)4096 * 768) return;
    int r = (int)(i4 / 768), n = (int)(i4 % 768);
    int s = r & 511;
    float4 a = *(float4*)(h + i4);
    float4 b = *(const float4*)(pos + (size_t)s * 768 + n);
    a.x += b.x; a.y += b.y; a.z += b.z; a.w += b.w;
    *(float4*)(h + i4) = a;
}

// dq[(b*128+p)*512+c] = dec_query[p*512+c]
__global__ void dqinit_k(float* __restrict__ dq, const float* __restrict__ q0) {
    size_t i4 = ((size_t)blockIdx.x * 256 + threadIdx.x) * 4;
    if (i4 >= (size_t)1024 * 512) return;
    int row = (int)(i4 / 512), col = (int)(i4 % 512);
    int p = row & 127;
    *(float4*)(dq + i4) = *(const float4*)(q0 + (size_t)p * 512 + col);
}

// ---------------- layernorm: fp32 in -> bf16 out ----------------
__global__ __launch_bounds__(256) void ln_k(const float* __restrict__ X, unsigned short* __restrict__ Y,
                                            const float* __restrict__ sc, const float* __restrict__ bi,
                                            int cols) {
    int row = blockIdx.x;
    int t = threadIdx.x;
    const float* x = X + (size_t)row * cols;
    float s = 0.f, sq = 0.f;
    for (int c = t; c < cols; c += 256) { float v = x[c]; s += v; sq += v * v; }
    for (int o = 32; o; o >>= 1) { s += __shfl_xor(s, o); sq += __shfl_xor(sq, o); }
    __shared__ float rs[4], rq[4];
    if ((t & 63) == 0) { rs[t >> 6] = s; rq[t >> 6] = sq; }
    __syncthreads();
    s = rs[0] + rs[1] + rs[2] + rs[3];
    sq = rq[0] + rq[1] + rq[2] + rq[3];
    float mean = s / cols;
    float var = sq / cols - mean * mean;
    float inv = rsqrtf(var + 1e-5f);
    unsigned short* y = Y + (size_t)row * cols;
    for (int c = t; c < cols; c += 256) {
        float v = (x[c] - mean) * inv;
        y[c] = f2bf(v * sc[c] + bi[c]);
    }
}

// ---------------- bf16 MFMA GEMM (m97 structure) ----------------
// A: MxK bf16 row-major. Bt: NxK bf16 row-major (= B^T). C = epi(A@B + bias)(+res).
// M%128==0, N%128==0, K%64==0. Tile 128x128, BK=64, 4 waves each 64x64.
__global__ __launch_bounds__(256) void mgemm_k(const unsigned short* __restrict__ A,
                                               const unsigned short* __restrict__ Bt,
                                               const float* __restrict__ bias,
                                               const float* __restrict__ res,
                                               float* __restrict__ Cf,
                                               unsigned short* __restrict__ Cb,
                                               int M, int N, int K, int dogelu) {
    __shared__ unsigned short lA[128 * 64];
    __shared__ unsigned short lB[128 * 64];
    const int t = threadIdx.x, w = t >> 6, ln = t & 63;
    const int row0 = blockIdx.y * 128, col0 = blockIdx.x * 128;
    const int wr = w >> 1, wc = w & 1;

    f32x4 acc[4][4] = {};

    // staging sources (inverse-swizzled global addresses, rule #21)
    const unsigned short* gA[4];
    const unsigned short* gB[4];
    int ldsOff[4];
#pragma unroll
    for (int u = 0; u < 4; ++u) {
        int ch = u * 256 + w * 64 + ln;
        int r = ch >> 3, c = ch & 7;
        int sc_ = ((c ^ (r & 7)) << 3);
        gA[u] = A + (size_t)(row0 + r) * K + sc_;
        gB[u] = Bt + (size_t)(col0 + r) * K + sc_;
        ldsOff[u] = (u * 256 + w * 64) << 4; // wave-uniform byte base
    }
    // LDS fragment read offsets (elements), swizzled, k0-independent
    int offA[4][2], offB[4][2];
#pragma unroll
    for (int f = 0; f < 4; ++f)
#pragma unroll
        for (int kk = 0; kk < 2; ++kk) {
            int ra = wr * 64 + f * 16 + (ln & 15);
            offA[f][kk] = ra * 64 + (((kk * 4 + (ln >> 4)) ^ (ra & 7)) << 3);
            int rb = wc * 64 + f * 16 + (ln & 15);
            offB[f][kk] = rb * 64 + (((kk * 4 + (ln >> 4)) ^ (rb & 7)) << 3);
        }

    for (int k0 = 0; k0 < K; k0 += 64) {
#pragma unroll
        for (int u = 0; u < 4; ++u)
            GLDS(gA[u] + k0, (char*)lA + ldsOff[u]);
#pragma unroll
        for (int u = 0; u < 4; ++u)
            GLDS(gB[u] + k0, (char*)lB + ldsOff[u]);
        __syncthreads();
        bf16x8 av[4][2], bv[4][2];
#pragma unroll
        for (int f = 0; f < 4; ++f)
#pragma unroll
            for (int kk = 0; kk < 2; ++kk) {
                av[f][kk] = *(const bf16x8*)&lA[offA[f][kk]];
                bv[f][kk] = *(const bf16x8*)&lB[offB[f][kk]];
            }
#pragma unroll
        for (int kk = 0; kk < 2; ++kk)
#pragma unroll
            for (int i = 0; i < 4; ++i)
#pragma unroll
                for (int j = 0; j < 4; ++j)
                    acc[i][j] = __builtin_amdgcn_mfma_f32_16x16x32_bf16(av[i][kk], bv[j][kk], acc[i][j], 0, 0, 0);
        __syncthreads();
    }

    // epilogue: C/D layout col=lane&15, row=(lane>>4)*4+reg
    const int cl = ln & 15, rg = ln >> 4;
#pragma unroll
    for (int i = 0; i < 4; ++i) {
#pragma unroll
        for (int j = 0; j < 4; ++j) {
#pragma unroll
            for (int r = 0; r < 4; ++r) {
                int row = row0 + wr * 64 + i * 16 + rg * 4 + r;
                int col = col0 + wc * 64 + j * 16 + cl;
                float v = acc[i][j][r];
                if (bias) v += bias[col];
                if (dogelu) v = 0.5f * v * (1.0f + erff(v * 0.70710678118654752f));
                if (res) v += res[(size_t)row * N + col];
                if (Cf) Cf[(size_t)row * N + col] = v;
                if (Cb) Cb[(size_t)row * N + col] = f2bf(v);
            }
        }
    }
}

// ---------------- attention: scores + softmax -> P (fp32) ----------------
__global__ __launch_bounds__(256) void attn_score_k(const float* __restrict__ Qp, const float* __restrict__ Kp,
                                                    float* __restrict__ Pp,
                                                    int q_rstride, int k_rstride, int Sq, int Sk, int nh,
                                                    float scale, const int* __restrict__ blk, int b0) {
    __shared__ float qt[16][68];
    __shared__ float kt[64][68];
    __shared__ float sc[16][516];
    const int t = threadIdx.x;
    const int bh = blockIdx.x;
    const int lb = bh / nh, hh = bh % nh;
    const int b = b0 + lb;
    const int q0 = blockIdx.y * 16;
    const int tq = q0 >> 7;

    { // stage 16x64 q tile
        int r = t >> 4, c = (t & 15) * 4;
        const float* src = Qp + (size_t)(b * Sq + q0 + r) * q_rstride + hh * 64 + c;
        *(float4*)&qt[r][c] = *(const float4*)src;
    }

    const int ql = t & 15, kg = t >> 4;
    for (int kc = 0; kc < Sk; kc += 64) {
        bool skip = false;
        if (blk) skip = blk[tq * 4 + (kc >> 7)] != 0;
        if (skip) continue;
        __syncthreads();
        { // stage 64x64 K chunk
            int r = t >> 2, c0 = (t & 3) * 16;
            const float* src = Kp + (size_t)(b * Sk + kc + r) * k_rstride + hh * 64 + c0;
#pragma unroll
            for (int u = 0; u < 4; ++u)
                *(float4*)&kt[r][c0 + u * 4] = *(const float4*)(src + u * 4);
        }
        __syncthreads();
        float s0 = 0.f, s1 = 0.f, s2 = 0.f, s3 = 0.f;
#pragma unroll
        for (int d = 0; d < 64; d += 4) {
            float4 qv = *(const float4*)&qt[ql][d];
            float4 k0v = *(const float4*)&kt[kg * 4 + 0][d];
            float4 k1v = *(const float4*)&kt[kg * 4 + 1][d];
            float4 k2v = *(const float4*)&kt[kg * 4 + 2][d];
            float4 k3v = *(const float4*)&kt[kg * 4 + 3][d];
            s0 += qv.x * k0v.x + qv.y * k0v.y + qv.z * k0v.z + qv.w * k0v.w;
            s1 += qv.x * k1v.x + qv.y * k1v.y + qv.z * k1v.z + qv.w * k1v.w;
            s2 += qv.x * k2v.x + qv.y * k2v.y + qv.z * k2v.z + qv.w * k2v.w;
            s3 += qv.x * k3v.x + qv.y * k3v.y + qv.z * k3v.z + qv.w * k3v.w;
        }
        sc[ql][kc + kg * 4 + 0] = s0 * scale;
        sc[ql][kc + kg * 4 + 1] = s1 * scale;
        sc[ql][kc + kg * 4 + 2] = s2 * scale;
        sc[ql][kc + kg * 4 + 3] = s3 * scale;
    }
    __syncthreads();

    const int wave = t >> 6, lane = t & 63;
    const int nchunk = Sk >> 6;
    for (int r = wave; r < 16; r += 4) {
        float vals[8];
        float m = -1e30f;
        for (int i = 0; i < nchunk; ++i) {
            bool ok = true;
            if (blk) ok = blk[tq * 4 + ((i * 64) >> 7)] == 0;
            vals[i] = ok ? sc[r][i * 64 + lane] : -1e30f;
            m = fmaxf(m, vals[i]);
        }
        for (int o = 32; o; o >>= 1) m = fmaxf(m, __shfl_xor(m, o));
        float ssum = 0.f;
        for (int i = 0; i < nchunk; ++i) {
            float e = (vals[i] > -1e29f) ? __expf(vals[i] - m) : 0.f;
            vals[i] = e;
            ssum += e;
        }
        for (int o = 32; o; o >>= 1) ssum += __shfl_xor(ssum, o);
        float inv = 1.f / ssum;
        float* pr = Pp + ((size_t)(lb * nh + hh) * Sq + q0 + r) * Sk;
        for (int i = 0; i < nchunk; ++i) pr[i * 64 + lane] = vals[i] * inv;
    }
}

// ---------------- attention: O = P @ V  (fp32 in, bf16 out) ----------------
__global__ __launch_bounds__(256) void attn_pv_k(const float* __restrict__ Pp, const float* __restrict__ Vp,
                                                 unsigned short* __restrict__ Op,
                                                 int v_rstride, int o_rstride, int Sq, int Sk, int nh,
                                                 const int* __restrict__ blk, int b0) {
    __shared__ float Vs[128][68];
    const int t = threadIdx.x;
    const int bh = blockIdx.x;
    const int lb = bh / nh, hh = bh % nh;
    const int b = b0 + lb;
    const int q0 = blockIdx.y * 4;
    const int ql = t >> 6, d = t & 63;
    const int q = q0 + ql;
    const int tq = q >> 7;
    const float* prow = Pp + ((size_t)(lb * nh + hh) * Sq + q) * Sk;
    float acc = 0.f;
    for (int kc = 0; kc < Sk; kc += 128) {
        bool skip = false;
        if (blk) skip = blk[tq * 4 + (kc >> 7)] != 0;
        if (skip) continue;
        __syncthreads();
#pragma unroll
        for (int u = 0; u < 8; ++u) {
            int idx = t + u * 256;
            int r = idx >> 4, c = (idx & 15) * 4;
            const float* src = Vp + (size_t)(b * Sk + kc + r) * v_rstride + hh * 64 + c;
            *(float4*)&Vs[r][c] = *(const float4*)src;
        }
        __syncthreads();
#pragma unroll 4
        for (int j = 0; j < 128; ++j) acc += prow[kc + j] * Vs[j][d];
    }
    Op[(size_t)(b * Sq + q) * o_rstride + hh * 64 + d] = f2bf(acc);
}

// ---------------- host ----------------
extern "C" void kernel_launch(void* const* d_in, const int* in_sizes, int n_in,
                              void* d_out, int out_size, void* d_ws, size_t ws_size,
                              hipStream_t stream) {
    (void)in_sizes; (void)n_in; (void)out_size;
    const float* x          = (const float*)d_in[0];
    const float* mask_rand  = (const float*)d_in[1];
    const float* conv_w     = (const float*)d_in[2];
    const float* conv_b     = (const float*)d_in[3];
    const float* pos_emb    = (const float*)d_in[4];
    const float* enc_ln1_s  = (const float*)d_in[5];
    const float* enc_ln1_b  = (const float*)d_in[6];
    const float* enc_qkv_w  = (const float*)d_in[7];
    const float* enc_proj_w = (const float*)d_in[8];
    const float* enc_proj_b = (const float*)d_in[9];
    const float* enc_ln2_s  = (const float*)d_in[10];
    const float* enc_ln2_b  = (const float*)d_in[11];
    const float* enc_mlp_w1 = (const float*)d_in[12];
    const float* enc_mlp_b1 = (const float*)d_in[13];
    const float* enc_mlp_w2 = (const float*)d_in[14];
    const float* enc_mlp_b2 = (const float*)d_in[15];
    const float* e2d_w      = (const float*)d_in[16];
    const float* e2d_b      = (const float*)d_in[17];
    const float* dec_query  = (const float*)d_in[18];
    const float* dec_ln1_s  = (const float*)d_in[19];
    const float* dec_ln1_b  = (const float*)d_in[20];
    const float* dec_qkv_w  = (const float*)d_in[21];
    const float* dec_qkv_b  = (const float*)d_in[22];
    const float* dec_out_w  = (const float*)d_in[23];
    const float* dec_out_b  = (const float*)d_in[24];
    const float* dec_ln2_s  = (const float*)d_in[25];
    const float* dec_ln2_b  = (const float*)d_in[26];
    const float* dec_mlp_w1 = (const float*)d_in[27];
    const float* dec_mlp_b1 = (const float*)d_in[28];
    const float* dec_mlp_w2 = (const float*)d_in[29];
    const float* dec_mlp_b2 = (const float*)d_in[30];
    const float* head_ln_s  = (const float*)d_in[31];
    const float* head_ln_b  = (const float*)d_in[32];
    const float* head_w     = (const float*)d_in[33];
    const float* head_b     = (const float*)d_in[34];
    float* outp = (float*)d_out;

    // workspace layout (float units)
    float* w = (float*)d_ws;
    size_t off = 0;
    int* blockedp = (int*)w; off += 128;
    float* h_buf = w + off; off += (size_t)4096 * 768;                  // fp32 residual
    unsigned short* y_bf = (unsigned short*)(w + off); off += (size_t)4096 * 768 / 2;   // bf16 LN/attnO
    float* qkv_buf = w + off; off += (size_t)4096 * 2304;               // fp32 qkv / dec QKV
    unsigned short* mlp_bf = (unsigned short*)(w + off); off += (size_t)4096 * 3072 / 2; // bf16 mlp / xf
    unsigned short* mem_bf = (unsigned short*)(w + off); off += (size_t)4096 * 512 / 2;
    float* dq_buf = w + off; off += (size_t)1024 * 512;
    unsigned short* convW_bf = (unsigned short*)(w + off); off += (size_t)768 * 3072 / 2;
    unsigned short* e2dT_bf = (unsigned short*)(w + off); off += (size_t)512 * 768 / 2;
    unsigned short* headT_bf = (unsigned short*)(w + off); off += (size_t)768 * 512 / 2;
    unsigned short* wbuf = (unsigned short*)(w + off); off += (size_t)3072 * 768 / 2;   // per-layer weight slot
    float* p_buf = w + off;
    size_t avail = (ws_size / 4 > off) ? (ws_size / 4 - off) : 0;
    int NBe = 8;
    while (NBe > 1 && (size_t)NBe * NH_ * S_ * S_ > avail) NBe >>= 1;
    int NBd = 8;
    while (NBd > 1 && (size_t)NBd * NHD_ * P_ * S_ > avail) NBd >>= 1;

    unsigned short* xf_bf = mlp_bf;
    const float* fnull = nullptr;
    float* f32null = nullptr;
    unsigned short* bfnull = nullptr;
    const float scale = 0.125f;

    hipLaunchKernelGGL(mask_k, dim3(1), dim3(128), 0, stream, mask_rand, blockedp);
    // conv weight: already N x K layout -> cast only
    hipLaunchKernelGGL(cast_k, dim3((768 * 3072 / 4 + 255) / 256), dim3(256), 0, stream,
                       conv_w, convW_bf, 768 * 3072 / 4);
    hipLaunchKernelGGL(wtrans_k, dim3(512 / 32, 768 / 32, 1), dim3(256), 0, stream, e2d_w, e2dT_bf, 768, 512);
    hipLaunchKernelGGL(wtrans_k, dim3(768 / 32, 512 / 32, 1), dim3(256), 0, stream, head_w, headT_bf, 512, 768);
    // patchify
    hipLaunchKernelGGL(gather_k, dim3(12288), dim3(256), 0, stream, x, xf_bf);
    hipLaunchKernelGGL(mgemm_k, dim3(768 / 128, 4096 / 128), dim3(256), 0, stream,
                       xf_bf, convW_bf, conv_b, fnull, h_buf, bfnull, 4096, 768, 3072, 0);
    hipLaunchKernelGGL(addpos_k, dim3(3072), dim3(256), 0, stream, h_buf, pos_emb);

    // -------- encoder --------
    for (int l = 0; l < L_; ++l) {
        const int* blk = blockedp + l * 16;
        hipLaunchKernelGGL(ln_k, dim3(4096), dim3(256), 0, stream,
                           h_buf, y_bf, enc_ln1_s + l * 768, enc_ln1_b + l * 768, 768);
        hipLaunchKernelGGL(wtrans_k, dim3(2304 / 32, 768 / 32, 1), dim3(256), 0, stream,
                           enc_qkv_w + (size_t)l * 768 * 2304, wbuf, 768, 2304);
        hipLaunchKernelGGL(mgemm_k, dim3(2304 / 128, 4096 / 128), dim3(256), 0, stream,
                           y_bf, wbuf, fnull, fnull, qkv_buf, bfnull, 4096, 2304, 768, 0);
        for (int b0 = 0; b0 < B_; b0 += NBe) {
            int nb = (B_ - b0 < NBe) ? (B_ - b0) : NBe;
            hipLaunchKernelGGL(attn_score_k, dim3(NH_ * nb, S_ / 16), dim3(256), 0, stream,
                               qkv_buf, qkv_buf + 768, p_buf, 2304, 2304, S_, S_, NH_, scale, blk, b0);
            hipLaunchKernelGGL(attn_pv_k, dim3(NH_ * nb, S_ / 4), dim3(256), 0, stream,
                               p_buf, qkv_buf + 1536, y_bf, 2304, 768, S_, S_, NH_, blk, b0);
        }
        hipLaunchKernelGGL(wtrans_k, dim3(768 / 32, 768 / 32, 1), dim3(256), 0, stream,
                           enc_proj_w + (size_t)l * 768 * 768, wbuf, 768, 768);
        hipLaunchKernelGGL(mgemm_k, dim3(768 / 128, 4096 / 128), dim3(256), 0, stream,
                           y_bf, wbuf, enc_proj_b + l * 768, h_buf, h_buf, bfnull, 4096, 768, 768, 0);
        hipLaunchKernelGGL(ln_k, dim3(4096), dim3(256), 0, stream,
                           h_buf, y_bf, enc_ln2_s + l * 768, enc_ln2_b + l * 768, 768);
        hipLaunchKernelGGL(wtrans_k, dim3(3072 / 32, 768 / 32, 1), dim3(256), 0, stream,
                           enc_mlp_w1 + (size_t)l * 768 * 3072, wbuf, 768, 3072);
        hipLaunchKernelGGL(mgemm_k, dim3(3072 / 128, 4096 / 128), dim3(256), 0, stream,
                           y_bf, wbuf, enc_mlp_b1 + l * 3072, fnull, f32null, mlp_bf, 4096, 3072, 768, 1);
        hipLaunchKernelGGL(wtrans_k, dim3(768 / 32, 3072 / 32, 1), dim3(256), 0, stream,
                           enc_mlp_w2 + (size_t)l * 3072 * 768, wbuf, 3072, 768);
        hipLaunchKernelGGL(mgemm_k, dim3(768 / 128, 4096 / 128), dim3(256), 0, stream,
                           mlp_bf, wbuf, enc_mlp_b2 + l * 768, h_buf, h_buf, bfnull, 4096, 768, 3072, 0);
    }

    // -------- enc2dec --------
    hipLaunchKernelGGL(cast_k, dim3((4096 * 768 / 4 + 255) / 256), dim3(256), 0, stream,
                       h_buf, y_bf, 4096 * 768 / 4);
    hipLaunchKernelGGL(mgemm_k, dim3(512 / 128, 4096 / 128), dim3(256), 0, stream,
                       y_bf, e2dT_bf, e2d_b, fnull, f32null, mem_bf, 4096, 512, 768, 0);
    hipLaunchKernelGGL(dqinit_k, dim3(512), dim3(256), 0, stream, dq_buf, dec_query);

    // -------- decoder --------
    float* Qd = qkv_buf;
    float* Kd = qkv_buf + (size_t)1024 * 512;
    float* Vd = Kd + (size_t)4096 * 512;
    for (int l = 0; l < LD_; ++l) {
        hipLaunchKernelGGL(ln_k, dim3(1024), dim3(256), 0, stream,
                           dq_buf, y_bf, dec_ln1_s + l * 512, dec_ln1_b + l * 512, 512);
        hipLaunchKernelGGL(wtrans_k, dim3(512 / 32, 512 / 32, 3), dim3(256), 0, stream,
                           dec_qkv_w + (size_t)l * 3 * 512 * 512, wbuf, 512, 512);
        hipLaunchKernelGGL(mgemm_k, dim3(512 / 128, 1024 / 128), dim3(256), 0, stream,
                           y_bf, wbuf, dec_qkv_b + (l * 3 + 0) * 512, fnull, Qd, bfnull, 1024, 512, 512, 0);
        hipLaunchKernelGGL(mgemm_k, dim3(512 / 128, 4096 / 128), dim3(256), 0, stream,
                           mem_bf, wbuf + (size_t)512 * 512, dec_qkv_b + (l * 3 + 1) * 512, fnull, Kd, bfnull,
                           4096, 512, 512, 0);
        hipLaunchKernelGGL(mgemm_k, dim3(512 / 128, 4096 / 128), dim3(256), 0, stream,
                           mem_bf, wbuf + (size_t)2 * 512 * 512, dec_qkv_b + (l * 3 + 2) * 512, fnull, Vd, bfnull,
                           4096, 512, 512, 0);
        for (int b0 = 0; b0 < B_; b0 += NBd) {
            int nb = (B_ - b0 < NBd) ? (B_ - b0) : NBd;
            hipLaunchKernelGGL(attn_score_k, dim3(NHD_ * nb, P_ / 16), dim3(256), 0, stream,
                               Qd, Kd, p_buf, 512, 512, P_, S_, NHD_, scale, (const int*)nullptr, b0);
            hipLaunchKernelGGL(attn_pv_k, dim3(NHD_ * nb, P_ / 4), dim3(256), 0, stream,
                               p_buf, Vd, y_bf, 512, 512, P_, S_, NHD_, (const int*)nullptr, b0);
        }
        hipLaunchKernelGGL(wtrans_k, dim3(512 / 32, 512 / 32, 1), dim3(256), 0, stream,
                           dec_out_w + (size_t)l * 512 * 512, wbuf, 512, 512);
        hipLaunchKernelGGL(mgemm_k, dim3(512 / 128, 1024 / 128), dim3(256), 0, stream,
                           y_bf, wbuf, dec_out_b + l * 512, dq_buf, dq_buf, bfnull, 1024, 512, 512, 0);
        hipLaunchKernelGGL(ln_k, dim3(1024), dim3(256), 0, stream,
                           dq_buf, y_bf, dec_ln2_s + l * 512, dec_ln2_b + l * 512, 512);
        hipLaunchKernelGGL(wtrans_k, dim3(2048 / 32, 512 / 32, 1), dim3(256), 0, stream,
                           dec_mlp_w1 + (size_t)l * 512 * 2048, wbuf, 512, 2048);
        hipLaunchKernelGGL(mgemm_k, dim3(2048 / 128, 1024 / 128), dim3(256), 0, stream,
                           y_bf, wbuf, dec_mlp_b1 + l * 2048, fnull, f32null, mlp_bf, 1024, 2048, 512, 1);
        hipLaunchKernelGGL(wtrans_k, dim3(512 / 32, 2048 / 32, 1), dim3(256), 0, stream,
                           dec_mlp_w2 + (size_t)l * 2048 * 512, wbuf, 2048, 512);
        hipLaunchKernelGGL(mgemm_k, dim3(512 / 128, 1024 / 128), dim3(256), 0, stream,
                           mlp_bf, wbuf, dec_mlp_b2 + l * 512, dq_buf, dq_buf, bfnull, 1024, 512, 2048, 0);
    }

    // -------- head --------
    hipLaunchKernelGGL(ln_k, dim3(1024), dim3(256), 0, stream,
                       dq_buf, y_bf, head_ln_s, head_ln_b, 512);
    hipLaunchKernelGGL(mgemm_k, dim3(768 / 128, 1024 / 128), dim3(256), 0, stream,
                       y_bf, headT_bf, head_b, fnull, outp, bfnull, 1024, 768, 512, 0);
}

// Round 3
// 3557.099 us; speedup vs baseline: 4.9276x; 1.8911x over previous
//
#include <hip/hip_runtime.h>
#include <math.h>

// ---------------- dims ----------------
#define B_ 8
#define T_ 4
#define C_ 12
#define H_ 128
#define W_ 256
#define P_ 128
#define S_ 512
#define D_ 768
#define NH_ 12
#define HD_ 64
#define L_ 8
#define MLP_ 3072
#define DD_ 512
#define NHD_ 8
#define LD_ 4
#define MLPD_ 2048
#define OUT_ 768

typedef __bf16 bf16x8 __attribute__((ext_vector_type(8)));
typedef float f32x4 __attribute__((ext_vector_type(4)));

static __device__ __forceinline__ unsigned short f2bf(float f) {
    unsigned int u = __float_as_uint(f);
    unsigned int r = (u + 0x7fffu + ((u >> 16) & 1u)) >> 16;
    return (unsigned short)r;
}

#define GLDS(gp, lp) __builtin_amdgcn_global_load_lds( \
    (const __attribute__((address_space(1))) void*)(gp), \
    (__attribute__((address_space(3))) void*)(lp), 16, 0, 0)

// ---------------- small utility kernels ----------------

__global__ void mask_k(const float* __restrict__ mr, int* __restrict__ blocked) {
    int i = threadIdx.x; // 128 = L*T*T
    if (i < L_ * T_ * T_) {
        int tk = i & 3, tq = (i >> 2) & 3;
        blocked[i] = (mr[i] < 0.8f && tk > tq) ? 1 : 0;
    }
}

// batched transpose + cast: in (batch, Kd, Nd) fp32 -> out (batch, Nd, Kd) bf16
__global__ __launch_bounds__(256) void wtrans_k(const float* __restrict__ in, unsigned short* __restrict__ out,
                                                int Kd, int Nd) {
    __shared__ float tile[32][33];
    int n0 = blockIdx.x * 32, k0 = blockIdx.y * 32;
    size_t boff = (size_t)blockIdx.z * Kd * Nd;
    const float* src = in + boff;
    unsigned short* dst = out + boff;
    int tx = threadIdx.x & 31, ty = threadIdx.x >> 5; // 32 x 8
#pragma unroll
    for (int i = 0; i < 32; i += 8)
        tile[ty + i][tx] = src[(size_t)(k0 + ty + i) * Nd + n0 + tx];
    __syncthreads();
#pragma unroll
    for (int i = 0; i < 32; i += 8)
        dst[(size_t)(n0 + ty + i) * Kd + k0 + tx] = f2bf(tile[tx][ty + i]);
}

// linear cast fp32 -> bf16, n multiple of 4
__global__ void cast_k(const float* __restrict__ in, unsigned short* __restrict__ out, int n4) {
    int i = blockIdx.x * 256 + threadIdx.x;
    if (i >= n4) return;
    float4 v = *(const float4*)(in + (size_t)i * 4);
    uint2 o;
    o.x = (unsigned)f2bf(v.x) | ((unsigned)f2bf(v.y) << 16);
    o.y = (unsigned)f2bf(v.z) | ((unsigned)f2bf(v.w) << 16);
    *(uint2*)(out + (size_t)i * 4) = o;
}

// xf[bt, p, c*256+ph*16+pw] = x[bt, c, hp*16+ph, wp*16+pw]  (bf16 out)
__global__ void gather_k(const float* __restrict__ x, unsigned short* __restrict__ xf) {
    size_t i4 = ((size_t)blockIdx.x * 256 + threadIdx.x) * 4;
    if (i4 >= (size_t)4096 * 3072) return;
    int row = (int)(i4 / 3072), col = (int)(i4 % 3072);
    int bt = row >> 7, p = row & 127;
    int hp = p >> 4, wp = p & 15;
    int c = col >> 8, rem = col & 255;
    int ph = rem >> 4, pw0 = rem & 15; // multiple of 4
    const float* src = x + (((size_t)(bt * C_ + c) * H_ + hp * 16 + ph) * W_ + wp * 16 + pw0);
    float4 v = *(const float4*)src;
    uint2 o;
    o.x = (unsigned)f2bf(v.x) | ((unsigned)f2bf(v.y) << 16);
    o.y = (unsigned)f2bf(v.z) | ((unsigned)f2bf(v.w) << 16);
    *(uint2*)(xf + i4) = o;
}

// h[r][n] += pos_emb[r%512][n]
__global__ void addpos_k(float* __restrict__ h, const float* __restrict__ pos) {
    size_t i4 = ((size_t)blockIdx.x * 256 + threadIdx.x) * 4;
    if (i4 >= (size_t)4096 * 768) return;
    int r = (int)(i4 / 768), n = (int)(i4 % 768);
    int s = r & 511;
    float4 a = *(float4*)(h + i4);
    float4 b = *(const float4*)(pos + (size_t)s * 768 + n);
    a.x += b.x; a.y += b.y; a.z += b.z; a.w += b.w;
    *(float4*)(h + i4) = a;
}

// dq[(b*128+p)*512+c] = dec_query[p*512+c]
__global__ void dqinit_k(float* __restrict__ dq, const float* __restrict__ q0) {
    size_t i4 = ((size_t)blockIdx.x * 256 + threadIdx.x) * 4;
    if (i4 >= (size_t)1024 * 512) return;
    int row = (int)(i4 / 512), col = (int)(i4 % 512);
    int p = row & 127;
    *(float4*)(dq + i4) = *(const float4*)(q0 + (size_t)p * 512 + col);
}

// ---------------- layernorm: fp32 in -> bf16 out ----------------
__global__ __launch_bounds__(256) void ln_k(const float* __restrict__ X, unsigned short* __restrict__ Y,
                                            const float* __restrict__ sc, const float* __restrict__ bi,
                                            int cols) {
    int row = blockIdx.x;
    int t = threadIdx.x;
    const float* x = X + (size_t)row * cols;
    float s = 0.f, sq = 0.f;
    for (int c = t; c < cols; c += 256) { float v = x[c]; s += v; sq += v * v; }
    for (int o = 32; o; o >>= 1) { s += __shfl_xor(s, o); sq += __shfl_xor(sq, o); }
    __shared__ float rs[4], rq[4];
    if ((t & 63) == 0) { rs[t >> 6] = s; rq[t >> 6] = sq; }
    __syncthreads();
    s = rs[0] + rs[1] + rs[2] + rs[3];
    sq = rq[0] + rq[1] + rq[2] + rq[3];
    float mean = s / cols;
    float var = sq / cols - mean * mean;
    float inv = rsqrtf(var + 1e-5f);
    unsigned short* y = Y + (size_t)row * cols;
    for (int c = t; c < cols; c += 256) {
        float v = (x[c] - mean) * inv;
        y[c] = f2bf(v * sc[c] + bi[c]);
    }
}

// ---------------- bf16 MFMA GEMM (m97 structure) ----------------
// A: MxK bf16 row-major. Bt: NxK bf16 row-major (= B^T). C = epi(A@B + bias)(+res).
// M%128==0, N%128==0, K%64==0. Tile 128x128, BK=64, 4 waves each 64x64.
__global__ __launch_bounds__(256) void mgemm_k(const unsigned short* __restrict__ A,
                                               const unsigned short* __restrict__ Bt,
                                               const float* __restrict__ bias,
                                               const float* __restrict__ res,
                                               float* __restrict__ Cf,
                                               unsigned short* __restrict__ Cb,
                                               int M, int N, int K, int dogelu) {
    __shared__ unsigned short lA[128 * 64];
    __shared__ unsigned short lB[128 * 64];
    const int t = threadIdx.x, w = t >> 6, ln = t & 63;
    const int row0 = blockIdx.y * 128, col0 = blockIdx.x * 128;
    const int wr = w >> 1, wc = w & 1;

    f32x4 acc[4][4] = {};

    const unsigned short* gA[4];
    const unsigned short* gB[4];
    int ldsOff[4];
#pragma unroll
    for (int u = 0; u < 4; ++u) {
        int ch = u * 256 + w * 64 + ln;
        int r = ch >> 3, c = ch & 7;
        int sc_ = ((c ^ (r & 7)) << 3);
        gA[u] = A + (size_t)(row0 + r) * K + sc_;
        gB[u] = Bt + (size_t)(col0 + r) * K + sc_;
        ldsOff[u] = (u * 256 + w * 64) << 4; // wave-uniform byte base
    }
    int offA[4][2], offB[4][2];
#pragma unroll
    for (int f = 0; f < 4; ++f)
#pragma unroll
        for (int kk = 0; kk < 2; ++kk) {
            int ra = wr * 64 + f * 16 + (ln & 15);
            offA[f][kk] = ra * 64 + (((kk * 4 + (ln >> 4)) ^ (ra & 7)) << 3);
            int rb = wc * 64 + f * 16 + (ln & 15);
            offB[f][kk] = rb * 64 + (((kk * 4 + (ln >> 4)) ^ (rb & 7)) << 3);
        }

    for (int k0 = 0; k0 < K; k0 += 64) {
#pragma unroll
        for (int u = 0; u < 4; ++u)
            GLDS(gA[u] + k0, (char*)lA + ldsOff[u]);
#pragma unroll
        for (int u = 0; u < 4; ++u)
            GLDS(gB[u] + k0, (char*)lB + ldsOff[u]);
        __syncthreads();
        bf16x8 av[4][2], bv[4][2];
#pragma unroll
        for (int f = 0; f < 4; ++f)
#pragma unroll
            for (int kk = 0; kk < 2; ++kk) {
                av[f][kk] = *(const bf16x8*)&lA[offA[f][kk]];
                bv[f][kk] = *(const bf16x8*)&lB[offB[f][kk]];
            }
#pragma unroll
        for (int kk = 0; kk < 2; ++kk)
#pragma unroll
            for (int i = 0; i < 4; ++i)
#pragma unroll
                for (int j = 0; j < 4; ++j)
                    acc[i][j] = __builtin_amdgcn_mfma_f32_16x16x32_bf16(av[i][kk], bv[j][kk], acc[i][j], 0, 0, 0);
        __syncthreads();
    }

    const int cl = ln & 15, rg = ln >> 4;
#pragma unroll
    for (int i = 0; i < 4; ++i) {
#pragma unroll
        for (int j = 0; j < 4; ++j) {
#pragma unroll
            for (int r = 0; r < 4; ++r) {
                int row = row0 + wr * 64 + i * 16 + rg * 4 + r;
                int col = col0 + wc * 64 + j * 16 + cl;
                float v = acc[i][j][r];
                if (bias) v += bias[col];
                if (dogelu) v = 0.5f * v * (1.0f + erff(v * 0.70710678118654752f));
                if (res) v += res[(size_t)row * N + col];
                if (Cf) Cf[(size_t)row * N + col] = v;
                if (Cb) Cb[(size_t)row * N + col] = f2bf(v);
            }
        }
    }
}

// ---------------- fused flash attention (bf16 MFMA) ----------------
// One block: (b,h) x 64 q-rows; 4 waves x 16 q-rows. K-chunks of 64 keys.
// Q/K/V bf16 row-major at head offset hh*64 within row stride *_rstride.
// Masked encoder chunks (per 128-key T-block) skipped entirely.
__global__ __launch_bounds__(256) void fattn_k(
    const unsigned short* __restrict__ Qp, const unsigned short* __restrict__ Kp,
    const unsigned short* __restrict__ Vp, unsigned short* __restrict__ Op,
    int q_rstride, int kv_rstride, int o_rstride, int Sq, int Sk, int nh,
    float scale, const int* __restrict__ blk) {
    __shared__ unsigned short lK[64 * 64];
    __shared__ unsigned short lV[64 * 64];
    __shared__ unsigned short lP[4][16 * 64];
    const int t = threadIdx.x, wv = t >> 6, ln = t & 63;
    const int bh = blockIdx.x, b = bh / nh, hh = bh % nh;
    const int q0 = blockIdx.y * 64;
    const int tq = q0 >> 7;
    const int cl = ln & 15, rg = ln >> 4;

    // Q fragments: row = cl (relative), dims kk*32 + rg*8 .. +7
    bf16x8 qa[2];
    {
        const unsigned short* qrow = Qp + (size_t)(b * Sq + q0 + wv * 16 + cl) * q_rstride + hh * 64 + rg * 8;
        qa[0] = *(const bf16x8*)(qrow);
        qa[1] = *(const bf16x8*)(qrow + 32);
    }
    f32x4 oacc[4] = {};
    float mrow[4] = {-1e30f, -1e30f, -1e30f, -1e30f};
    float lrow[4] = {0.f, 0.f, 0.f, 0.f};

    // K staging source indices (inverse swizzle)
    int krr[2], kcc[2];
#pragma unroll
    for (int u = 0; u < 2; ++u) {
        int ch = u * 256 + t;
        krr[u] = ch >> 3;
        kcc[u] = ((ch & 7) ^ (krr[u] & 7)) << 3;
    }
    const int vk0 = (t >> 4) * 4, vd0 = (t & 15) * 4;

    for (int kc = 0; kc < Sk; kc += 64) {
        if (blk && blk[tq * 4 + (kc >> 7)]) continue;
        __syncthreads(); // protect previous chunk's LDS reads
        // stage K (swizzled, via global_load_lds)
#pragma unroll
        for (int u = 0; u < 2; ++u)
            GLDS(Kp + (size_t)(b * Sk + kc + krr[u]) * kv_rstride + hh * 64 + kcc[u],
                 (char*)lK + ((u * 256 + wv * 64) << 4));
        // stage V transposed: lV[d][key], slot swizzle (key>>3)^((d+(d>>3))&7)
        {
            unsigned short a0[4], a1[4], a2[4], a3[4];
            const unsigned short* s0 = Vp + (size_t)(b * Sk + kc + vk0 + 0) * kv_rstride + hh * 64 + vd0;
            const unsigned short* s1 = Vp + (size_t)(b * Sk + kc + vk0 + 1) * kv_rstride + hh * 64 + vd0;
            const unsigned short* s2 = Vp + (size_t)(b * Sk + kc + vk0 + 2) * kv_rstride + hh * 64 + vd0;
            const unsigned short* s3 = Vp + (size_t)(b * Sk + kc + vk0 + 3) * kv_rstride + hh * 64 + vd0;
            *(uint2*)a0 = *(const uint2*)s0;
            *(uint2*)a1 = *(const uint2*)s1;
            *(uint2*)a2 = *(const uint2*)s2;
            *(uint2*)a3 = *(const uint2*)s3;
#pragma unroll
            for (int j = 0; j < 4; ++j) {
                int d = vd0 + j;
                int slot = (vk0 >> 3) ^ ((d + (d >> 3)) & 7);
                unsigned short pk[4] = {a0[j], a1[j], a2[j], a3[j]};
                *(uint2*)&lV[d * 64 + (slot << 3) + (vk0 & 7)] = *(uint2*)pk;
            }
        }
        __syncthreads();

        // S = Q K^T  (C: row=q=rg*4+r, col=key=f*16+cl)
        f32x4 sacc[4] = {};
#pragma unroll
        for (int kk = 0; kk < 2; ++kk)
#pragma unroll
            for (int f = 0; f < 4; ++f) {
                int rk = f * 16 + cl;
                bf16x8 kb = *(const bf16x8*)&lK[rk * 64 + (((kk * 4 + rg) ^ (rk & 7)) << 3)];
                sacc[f] = __builtin_amdgcn_mfma_f32_16x16x32_bf16(qa[kk], kb, sacc[f], 0, 0, 0);
            }
        // online softmax over the 64-key chunk
        float cm[4] = {-1e30f, -1e30f, -1e30f, -1e30f};
#pragma unroll
        for (int f = 0; f < 4; ++f)
#pragma unroll
            for (int r = 0; r < 4; ++r) {
                float v = sacc[f][r] * scale;
                sacc[f][r] = v;
                cm[r] = fmaxf(cm[r], v);
            }
#pragma unroll
        for (int o = 8; o; o >>= 1)
#pragma unroll
            for (int r = 0; r < 4; ++r) cm[r] = fmaxf(cm[r], __shfl_xor(cm[r], o));
        float corr[4], rs[4];
#pragma unroll
        for (int r = 0; r < 4; ++r) {
            float nm = fmaxf(mrow[r], cm[r]);
            corr[r] = __expf(mrow[r] - nm);
            mrow[r] = nm;
            rs[r] = 0.f;
        }
#pragma unroll
        for (int f = 0; f < 4; ++f)
#pragma unroll
            for (int r = 0; r < 4; ++r) {
                float p = __expf(sacc[f][r] - mrow[r]);
                sacc[f][r] = p;
                rs[r] += p;
            }
#pragma unroll
        for (int o = 8; o; o >>= 1)
#pragma unroll
            for (int r = 0; r < 4; ++r) rs[r] += __shfl_xor(rs[r], o);
#pragma unroll
        for (int r = 0; r < 4; ++r) lrow[r] = lrow[r] * corr[r] + rs[r];
#pragma unroll
        for (int f = 0; f < 4; ++f)
#pragma unroll
            for (int r = 0; r < 4; ++r) oacc[f][r] *= corr[r];
        // P -> per-wave LDS (swizzled), then read as A-fragments
#pragma unroll
        for (int f = 0; f < 4; ++f)
#pragma unroll
            for (int r = 0; r < 4; ++r) {
                int q = rg * 4 + r, key = f * 16 + cl;
                lP[wv][q * 64 + (((key >> 3) ^ (q & 7)) << 3) + (key & 7)] = f2bf(sacc[f][r]);
            }
        // O += P V
#pragma unroll
        for (int kk = 0; kk < 2; ++kk) {
            bf16x8 pa = *(const bf16x8*)&lP[wv][cl * 64 + (((kk * 4 + rg) ^ (cl & 7)) << 3)];
#pragma unroll
            for (int f = 0; f < 4; ++f) {
                int d = f * 16 + cl;
                bf16x8 vb = *(const bf16x8*)&lV[d * 64 + (((kk * 4 + rg) ^ ((d + (d >> 3)) & 7)) << 3)];
                oacc[f] = __builtin_amdgcn_mfma_f32_16x16x32_bf16(pa, vb, oacc[f], 0, 0, 0);
            }
        }
    }

    float inv[4];
#pragma unroll
    for (int r = 0; r < 4; ++r) inv[r] = 1.f / lrow[r];
#pragma unroll
    for (int f = 0; f < 4; ++f)
#pragma unroll
        for (int r = 0; r < 4; ++r) {
            int q = q0 + wv * 16 + rg * 4 + r;
            int d = f * 16 + cl;
            Op[(size_t)(b * Sq + q) * o_rstride + hh * 64 + d] = f2bf(oacc[f][r] * inv[r]);
        }
}

// ---------------- host ----------------
extern "C" void kernel_launch(void* const* d_in, const int* in_sizes, int n_in,
                              void* d_out, int out_size, void* d_ws, size_t ws_size,
                              hipStream_t stream) {
    (void)in_sizes; (void)n_in; (void)out_size; (void)ws_size;
    const float* x          = (const float*)d_in[0];
    const float* mask_rand  = (const float*)d_in[1];
    const float* conv_w     = (const float*)d_in[2];
    const float* conv_b     = (const float*)d_in[3];
    const float* pos_emb    = (const float*)d_in[4];
    const float* enc_ln1_s  = (const float*)d_in[5];
    const float* enc_ln1_b  = (const float*)d_in[6];
    const float* enc_qkv_w  = (const float*)d_in[7];
    const float* enc_proj_w = (const float*)d_in[8];
    const float* enc_proj_b = (const float*)d_in[9];
    const float* enc_ln2_s  = (const float*)d_in[10];
    const float* enc_ln2_b  = (const float*)d_in[11];
    const float* enc_mlp_w1 = (const float*)d_in[12];
    const float* enc_mlp_b1 = (const float*)d_in[13];
    const float* enc_mlp_w2 = (const float*)d_in[14];
    const float* enc_mlp_b2 = (const float*)d_in[15];
    const float* e2d_w      = (const float*)d_in[16];
    const float* e2d_b      = (const float*)d_in[17];
    const float* dec_query  = (const float*)d_in[18];
    const float* dec_ln1_s  = (const float*)d_in[19];
    const float* dec_ln1_b  = (const float*)d_in[20];
    const float* dec_qkv_w  = (const float*)d_in[21];
    const float* dec_qkv_b  = (const float*)d_in[22];
    const float* dec_out_w  = (const float*)d_in[23];
    const float* dec_out_b  = (const float*)d_in[24];
    const float* dec_ln2_s  = (const float*)d_in[25];
    const float* dec_ln2_b  = (const float*)d_in[26];
    const float* dec_mlp_w1 = (const float*)d_in[27];
    const float* dec_mlp_b1 = (const float*)d_in[28];
    const float* dec_mlp_w2 = (const float*)d_in[29];
    const float* dec_mlp_b2 = (const float*)d_in[30];
    const float* head_ln_s  = (const float*)d_in[31];
    const float* head_ln_b  = (const float*)d_in[32];
    const float* head_w     = (const float*)d_in[33];
    const float* head_b     = (const float*)d_in[34];
    float* outp = (float*)d_out;

    // workspace layout (float units)
    float* w = (float*)d_ws;
    size_t off = 0;
    int* blockedp = (int*)w; off += 128;
    float* h_buf = w + off; off += (size_t)4096 * 768;                                   // fp32 residual
    unsigned short* y_bf = (unsigned short*)(w + off); off += (size_t)4096 * 768 / 2;    // bf16 LN/attnO
    unsigned short* qkv_bf = (unsigned short*)(w + off); off += (size_t)4096 * 2304 / 2; // bf16 qkv / dec QKV
    unsigned short* mlp_bf = (unsigned short*)(w + off); off += (size_t)4096 * 3072 / 2; // bf16 mlp / xf
    unsigned short* mem_bf = (unsigned short*)(w + off); off += (size_t)4096 * 512 / 2;
    float* dq_buf = w + off; off += (size_t)1024 * 512;
    unsigned short* convW_bf = (unsigned short*)(w + off); off += (size_t)768 * 3072 / 2;
    unsigned short* e2dT_bf = (unsigned short*)(w + off); off += (size_t)512 * 768 / 2;
    unsigned short* headT_bf = (unsigned short*)(w + off); off += (size_t)768 * 512 / 2;
    unsigned short* wbuf = (unsigned short*)(w + off); off += (size_t)3072 * 768 / 2;    // per-layer weight slot

    unsigned short* xf_bf = mlp_bf;
    const float* fnull = nullptr;
    float* f32null = nullptr;
    unsigned short* bfnull = nullptr;
    const float scale = 0.125f;

    hipLaunchKernelGGL(mask_k, dim3(1), dim3(128), 0, stream, mask_rand, blockedp);
    hipLaunchKernelGGL(cast_k, dim3((768 * 3072 / 4 + 255) / 256), dim3(256), 0, stream,
                       conv_w, convW_bf, 768 * 3072 / 4);
    hipLaunchKernelGGL(wtrans_k, dim3(512 / 32, 768 / 32, 1), dim3(256), 0, stream, e2d_w, e2dT_bf, 768, 512);
    hipLaunchKernelGGL(wtrans_k, dim3(768 / 32, 512 / 32, 1), dim3(256), 0, stream, head_w, headT_bf, 512, 768);
    hipLaunchKernelGGL(gather_k, dim3(12288), dim3(256), 0, stream, x, xf_bf);
    hipLaunchKernelGGL(mgemm_k, dim3(768 / 128, 4096 / 128), dim3(256), 0, stream,
                       xf_bf, convW_bf, conv_b, fnull, h_buf, bfnull, 4096, 768, 3072, 0);
    hipLaunchKernelGGL(addpos_k, dim3(3072), dim3(256), 0, stream, h_buf, pos_emb);

    // -------- encoder --------
    for (int l = 0; l < L_; ++l) {
        const int* blk = blockedp + l * 16;
        hipLaunchKernelGGL(ln_k, dim3(4096), dim3(256), 0, stream,
                           h_buf, y_bf, enc_ln1_s + l * 768, enc_ln1_b + l * 768, 768);
        hipLaunchKernelGGL(wtrans_k, dim3(2304 / 32, 768 / 32, 1), dim3(256), 0, stream,
                           enc_qkv_w + (size_t)l * 768 * 2304, wbuf, 768, 2304);
        hipLaunchKernelGGL(mgemm_k, dim3(2304 / 128, 4096 / 128), dim3(256), 0, stream,
                           y_bf, wbuf, fnull, fnull, f32null, qkv_bf, 4096, 2304, 768, 0);
        hipLaunchKernelGGL(fattn_k, dim3(B_ * NH_, S_ / 64), dim3(256), 0, stream,
                           qkv_bf, qkv_bf + 768, qkv_bf + 1536, y_bf,
                           2304, 2304, 768, S_, S_, NH_, scale, blk);
        hipLaunchKernelGGL(wtrans_k, dim3(768 / 32, 768 / 32, 1), dim3(256), 0, stream,
                           enc_proj_w + (size_t)l * 768 * 768, wbuf, 768, 768);
        hipLaunchKernelGGL(mgemm_k, dim3(768 / 128, 4096 / 128), dim3(256), 0, stream,
                           y_bf, wbuf, enc_proj_b + l * 768, h_buf, h_buf, bfnull, 4096, 768, 768, 0);
        hipLaunchKernelGGL(ln_k, dim3(4096), dim3(256), 0, stream,
                           h_buf, y_bf, enc_ln2_s + l * 768, enc_ln2_b + l * 768, 768);
        hipLaunchKernelGGL(wtrans_k, dim3(3072 / 32, 768 / 32, 1), dim3(256), 0, stream,
                           enc_mlp_w1 + (size_t)l * 768 * 3072, wbuf, 768, 3072);
        hipLaunchKernelGGL(mgemm_k, dim3(3072 / 128, 4096 / 128), dim3(256), 0, stream,
                           y_bf, wbuf, enc_mlp_b1 + l * 3072, fnull, f32null, mlp_bf, 4096, 3072, 768, 1);
        hipLaunchKernelGGL(wtrans_k, dim3(768 / 32, 3072 / 32, 1), dim3(256), 0, stream,
                           enc_mlp_w2 + (size_t)l * 3072 * 768, wbuf, 3072, 768);
        hipLaunchKernelGGL(mgemm_k, dim3(768 / 128, 4096 / 128), dim3(256), 0, stream,
                           mlp_bf, wbuf, enc_mlp_b2 + l * 768, h_buf, h_buf, bfnull, 4096, 768, 3072, 0);
    }

    // -------- enc2dec --------
    hipLaunchKernelGGL(cast_k, dim3((4096 * 768 / 4 + 255) / 256), dim3(256), 0, stream,
                       h_buf, y_bf, 4096 * 768 / 4);
    hipLaunchKernelGGL(mgemm_k, dim3(512 / 128, 4096 / 128), dim3(256), 0, stream,
                       y_bf, e2dT_bf, e2d_b, fnull, f32null, mem_bf, 4096, 512, 768, 0);
    hipLaunchKernelGGL(dqinit_k, dim3(512), dim3(256), 0, stream, dq_buf, dec_query);

    // -------- decoder --------
    unsigned short* Qd = qkv_bf;
    unsigned short* Kd = qkv_bf + (size_t)1024 * 512;
    unsigned short* Vd = Kd + (size_t)4096 * 512;
    for (int l = 0; l < LD_; ++l) {
        hipLaunchKernelGGL(ln_k, dim3(1024), dim3(256), 0, stream,
                           dq_buf, y_bf, dec_ln1_s + l * 512, dec_ln1_b + l * 512, 512);
        hipLaunchKernelGGL(wtrans_k, dim3(512 / 32, 512 / 32, 3), dim3(256), 0, stream,
                           dec_qkv_w + (size_t)l * 3 * 512 * 512, wbuf, 512, 512);
        hipLaunchKernelGGL(mgemm_k, dim3(512 / 128, 1024 / 128), dim3(256), 0, stream,
                           y_bf, wbuf, dec_qkv_b + (l * 3 + 0) * 512, fnull, f32null, Qd, 1024, 512, 512, 0);
        hipLaunchKernelGGL(mgemm_k, dim3(512 / 128, 4096 / 128), dim3(256), 0, stream,
                           mem_bf, wbuf + (size_t)512 * 512, dec_qkv_b + (l * 3 + 1) * 512, fnull, f32null, Kd,
                           4096, 512, 512, 0);
        hipLaunchKernelGGL(mgemm_k, dim3(512 / 128, 4096 / 128), dim3(256), 0, stream,
                           mem_bf, wbuf + (size_t)2 * 512 * 512, dec_qkv_b + (l * 3 + 2) * 512, fnull, f32null, Vd,
                           4096, 512, 512, 0);
        hipLaunchKernelGGL(fattn_k, dim3(B_ * NHD_, P_ / 64), dim3(256), 0, stream,
                           Qd, Kd, Vd, y_bf, 512, 512, 512, P_, S_, NHD_, scale, (const int*)nullptr);
        hipLaunchKernelGGL(wtrans_k, dim3(512 / 32, 512 / 32, 1), dim3(256), 0, stream,
                           dec_out_w + (size_t)l * 512 * 512, wbuf, 512, 512);
        hipLaunchKernelGGL(mgemm_k, dim3(512 / 128, 1024 / 128), dim3(256), 0, stream,
                           y_bf, wbuf, dec_out_b + l * 512, dq_buf, dq_buf, bfnull, 1024, 512, 512, 0);
        hipLaunchKernelGGL(ln_k, dim3(1024), dim3(256), 0, stream,
                           dq_buf, y_bf, dec_ln2_s + l * 512, dec_ln2_b + l * 512, 512);
        hipLaunchKernelGGL(wtrans_k, dim3(2048 / 32, 512 / 32, 1), dim3(256), 0, stream,
                           dec_mlp_w1 + (size_t)l * 512 * 2048, wbuf, 512, 2048);
        hipLaunchKernelGGL(mgemm_k, dim3(2048 / 128, 1024 / 128), dim3(256), 0, stream,
                           y_bf, wbuf, dec_mlp_b1 + l * 2048, fnull, f32null, mlp_bf, 1024, 2048, 512, 1);
        hipLaunchKernelGGL(wtrans_k, dim3(512 / 32, 2048 / 32, 1), dim3(256), 0, stream,
                           dec_mlp_w2 + (size_t)l * 2048 * 512, wbuf, 2048, 512);
        hipLaunchKernelGGL(mgemm_k, dim3(512 / 128, 1024 / 128), dim3(256), 0, stream,
                           mlp_bf, wbuf, dec_mlp_b2 + l * 512, dq_buf, dq_buf, bfnull, 1024, 512, 2048, 0);
    }

    // -------- head --------
    hipLaunchKernelGGL(ln_k, dim3(1024), dim3(256), 0, stream,
                       dq_buf, y_bf, head_ln_s, head_ln_b, 512);
    hipLaunchKernelGGL(mgemm_k, dim3(768 / 128, 1024 / 128), dim3(256), 0, stream,
                       y_bf, headT_bf, head_b, fnull, outp, bfnull, 1024, 768, 512, 0);
}

// Round 4
// 3105.061 us; speedup vs baseline: 5.6450x; 1.1456x over previous
//
#include <hip/hip_runtime.h>
#include <math.h>

// ---------------- dims ----------------
#define B_ 8
#define T_ 4
#define C_ 12
#define H_ 128
#define W_ 256
#define P_ 128
#define S_ 512
#define D_ 768
#define NH_ 12
#define HD_ 64
#define L_ 8
#define MLP_ 3072
#define DD_ 512
#define NHD_ 8
#define LD_ 4
#define MLPD_ 2048
#define OUT_ 768

typedef __bf16 bf16x8 __attribute__((ext_vector_type(8)));
typedef float f32x4 __attribute__((ext_vector_type(4)));

static __device__ __forceinline__ unsigned short f2bf(float f) {
    unsigned int u = __float_as_uint(f);
    unsigned int r = (u + 0x7fffu + ((u >> 16) & 1u)) >> 16;
    return (unsigned short)r;
}

#define GLDS(gp, lp) __builtin_amdgcn_global_load_lds( \
    (const __attribute__((address_space(1))) void*)(gp), \
    (__attribute__((address_space(3))) void*)(lp), 16, 0, 0)

// ---------------- small utility kernels ----------------

__global__ void mask_k(const float* __restrict__ mr, int* __restrict__ blocked) {
    int i = threadIdx.x; // 128 = L*T*T
    if (i < L_ * T_ * T_) {
        int tk = i & 3, tq = (i >> 2) & 3;
        blocked[i] = (mr[i] < 0.8f && tk > tq) ? 1 : 0;
    }
}

// batched transpose + cast: in (batch, Kd, Nd) fp32 -> out (batch, Nd, Kd) bf16
__global__ __launch_bounds__(256) void wtrans_k(const float* __restrict__ in, unsigned short* __restrict__ out,
                                                int Kd, int Nd) {
    __shared__ float tile[32][33];
    int n0 = blockIdx.x * 32, k0 = blockIdx.y * 32;
    size_t boff = (size_t)blockIdx.z * Kd * Nd;
    const float* src = in + boff;
    unsigned short* dst = out + boff;
    int tx = threadIdx.x & 31, ty = threadIdx.x >> 5; // 32 x 8
#pragma unroll
    for (int i = 0; i < 32; i += 8)
        tile[ty + i][tx] = src[(size_t)(k0 + ty + i) * Nd + n0 + tx];
    __syncthreads();
#pragma unroll
    for (int i = 0; i < 32; i += 8)
        dst[(size_t)(n0 + ty + i) * Kd + k0 + tx] = f2bf(tile[tx][ty + i]);
}

// one encoder layer: transpose all 4 weights in one launch (6912 tile-blocks)
__global__ __launch_bounds__(256) void wtransenc_k(const float* __restrict__ s0, const float* __restrict__ s1,
                                                   const float* __restrict__ s2, const float* __restrict__ s3,
                                                   unsigned short* __restrict__ d0, unsigned short* __restrict__ d1,
                                                   unsigned short* __restrict__ d2, unsigned short* __restrict__ d3) {
    __shared__ float tile[32][33];
    int bid = blockIdx.x;
    const float* src; unsigned short* dst; int Kd, Nd, tt;
    if (bid < 1728)      { src = s0; dst = d0; Kd = 768;  Nd = 2304; tt = bid; }
    else if (bid < 2304) { src = s1; dst = d1; Kd = 768;  Nd = 768;  tt = bid - 1728; }
    else if (bid < 4608) { src = s2; dst = d2; Kd = 768;  Nd = 3072; tt = bid - 2304; }
    else                 { src = s3; dst = d3; Kd = 3072; Nd = 768;  tt = bid - 4608; }
    int nT = Nd >> 5;
    int n0 = (tt % nT) * 32, k0 = (tt / nT) * 32;
    int tx = threadIdx.x & 31, ty = threadIdx.x >> 5;
#pragma unroll
    for (int i = 0; i < 32; i += 8)
        tile[ty + i][tx] = src[(size_t)(k0 + ty + i) * Nd + n0 + tx];
    __syncthreads();
#pragma unroll
    for (int i = 0; i < 32; i += 8)
        dst[(size_t)(n0 + ty + i) * Kd + k0 + tx] = f2bf(tile[tx][ty + i]);
}

// linear cast fp32 -> bf16, n multiple of 4
__global__ void cast_k(const float* __restrict__ in, unsigned short* __restrict__ out, int n4) {
    int i = blockIdx.x * 256 + threadIdx.x;
    if (i >= n4) return;
    float4 v = *(const float4*)(in + (size_t)i * 4);
    uint2 o;
    o.x = (unsigned)f2bf(v.x) | ((unsigned)f2bf(v.y) << 16);
    o.y = (unsigned)f2bf(v.z) | ((unsigned)f2bf(v.w) << 16);
    *(uint2*)(out + (size_t)i * 4) = o;
}

// xf[bt, p, c*256+ph*16+pw] = x[bt, c, hp*16+ph, wp*16+pw]  (bf16 out)
__global__ void gather_k(const float* __restrict__ x, unsigned short* __restrict__ xf) {
    size_t i4 = ((size_t)blockIdx.x * 256 + threadIdx.x) * 4;
    if (i4 >= (size_t)4096 * 3072) return;
    int row = (int)(i4 / 3072), col = (int)(i4 % 3072);
    int bt = row >> 7, p = row & 127;
    int hp = p >> 4, wp = p & 15;
    int c = col >> 8, rem = col & 255;
    int ph = rem >> 4, pw0 = rem & 15;
    const float* src = x + (((size_t)(bt * C_ + c) * H_ + hp * 16 + ph) * W_ + wp * 16 + pw0);
    float4 v = *(const float4*)src;
    uint2 o;
    o.x = (unsigned)f2bf(v.x) | ((unsigned)f2bf(v.y) << 16);
    o.y = (unsigned)f2bf(v.z) | ((unsigned)f2bf(v.w) << 16);
    *(uint2*)(xf + i4) = o;
}

// dq[(b*128+p)*512+c] = dec_query[p*512+c]
__global__ void dqinit_k(float* __restrict__ dq, const float* __restrict__ q0) {
    size_t i4 = ((size_t)blockIdx.x * 256 + threadIdx.x) * 4;
    if (i4 >= (size_t)1024 * 512) return;
    int row = (int)(i4 / 512), col = (int)(i4 % 512);
    int p = row & 127;
    *(float4*)(dq + i4) = *(const float4*)(q0 + (size_t)p * 512 + col);
}

// ---------------- layernorm: fp32 in -> bf16 out ----------------
__global__ __launch_bounds__(256) void ln_k(const float* __restrict__ X, unsigned short* __restrict__ Y,
                                            const float* __restrict__ sc, const float* __restrict__ bi,
                                            int cols) {
    int row = blockIdx.x;
    int t = threadIdx.x;
    const float* x = X + (size_t)row * cols;
    float s = 0.f, sq = 0.f;
    for (int c = t; c < cols; c += 256) { float v = x[c]; s += v; sq += v * v; }
    for (int o = 32; o; o >>= 1) { s += __shfl_xor(s, o); sq += __shfl_xor(sq, o); }
    __shared__ float rs[4], rq[4];
    if ((t & 63) == 0) { rs[t >> 6] = s; rq[t >> 6] = sq; }
    __syncthreads();
    s = rs[0] + rs[1] + rs[2] + rs[3];
    sq = rq[0] + rq[1] + rq[2] + rq[3];
    float mean = s / cols;
    float var = sq / cols - mean * mean;
    float inv = rsqrtf(var + 1e-5f);
    unsigned short* y = Y + (size_t)row * cols;
    for (int c = t; c < cols; c += 256) {
        float v = (x[c] - mean) * inv;
        y[c] = f2bf(v * sc[c] + bi[c]);
    }
}

// ---------------- bf16 MFMA GEMM: double-buffered, counted vmcnt ----------------
// A: MxK bf16 row-major. Bt: NxK bf16 row-major (= B^T). C = epi(A@B + bias)(+res).
// Tile 128x128, BK=64, 4 waves. LDS 64KB (2 buffers). Grouped via blockIdx.z strides.
__global__ __launch_bounds__(256, 2) void mgemm_k(const unsigned short* __restrict__ A,
                                                  const unsigned short* __restrict__ Bt,
                                                  const float* __restrict__ bias,
                                                  const float* __restrict__ res,
                                                  float* Cf, unsigned short* Cb,
                                                  int N, int K, int dogelu, int resMask,
                                                  long long aBS, long long bBS, long long cBS, long long biasBS) {
    __shared__ unsigned short lA[2][128 * 64];
    __shared__ unsigned short lB[2][128 * 64];
    const int t = threadIdx.x, w = t >> 6, ln = t & 63;

    // batch (grouped) offsets
    const int z = blockIdx.z;
    A += (size_t)z * aBS;
    Bt += (size_t)z * bBS;
    if (bias) bias += (size_t)z * biasBS;
    if (Cf) Cf += (size_t)z * cBS;
    if (Cb) Cb += (size_t)z * cBS;

    // bijective XCD swizzle (m204)
    int nwg = gridDim.x * gridDim.y;
    int orig = blockIdx.y * gridDim.x + blockIdx.x;
    int qq = nwg >> 3, rr = nwg & 7;
    int xcd = orig & 7, lid = orig >> 3;
    int swz = (xcd < rr) ? (xcd * (qq + 1) + lid) : (rr * (qq + 1) + (xcd - rr) * qq + lid);
    const int row0 = (swz / gridDim.x) * 128, col0 = (swz % gridDim.x) * 128;
    const int wr = w >> 1, wc = w & 1;

    f32x4 acc[4][4] = {};

    // staging sources (inverse-swizzled global addresses)
    const unsigned short* gA[4];
    const unsigned short* gB[4];
    int ldsOff[4];
#pragma unroll
    for (int u = 0; u < 4; ++u) {
        int ch = u * 256 + w * 64 + ln;
        int r = ch >> 3, c = ch & 7;
        int sc_ = ((c ^ (r & 7)) << 3);
        gA[u] = A + (size_t)(row0 + r) * K + sc_;
        gB[u] = Bt + (size_t)(col0 + r) * K + sc_;
        ldsOff[u] = (u * 256 + w * 64) << 4; // wave-uniform byte base
    }
    // LDS fragment read offsets (elements), swizzled
    int offA[4][2], offB[4][2];
#pragma unroll
    for (int f = 0; f < 4; ++f)
#pragma unroll
        for (int kk = 0; kk < 2; ++kk) {
            int ra = wr * 64 + f * 16 + (ln & 15);
            offA[f][kk] = ra * 64 + (((kk * 4 + (ln >> 4)) ^ (ra & 7)) << 3);
            int rb = wc * 64 + f * 16 + (ln & 15);
            offB[f][kk] = rb * 64 + (((kk * 4 + (ln >> 4)) ^ (rb & 7)) << 3);
        }

    const int nt = K >> 6;
    // prologue: stage tile 0 into buffer 0
#pragma unroll
    for (int u = 0; u < 4; ++u) GLDS(gA[u], (char*)&lA[0][0] + ldsOff[u]);
#pragma unroll
    for (int u = 0; u < 4; ++u) GLDS(gB[u], (char*)&lB[0][0] + ldsOff[u]);

    for (int tt = 0; tt < nt; ++tt) {
        const int cur = tt & 1;
        if (tt + 1 < nt) {
            const int koff = (tt + 1) << 6;
#pragma unroll
            for (int u = 0; u < 4; ++u) GLDS(gA[u] + koff, (char*)&lA[cur ^ 1][0] + ldsOff[u]);
#pragma unroll
            for (int u = 0; u < 4; ++u) GLDS(gB[u] + koff, (char*)&lB[cur ^ 1][0] + ldsOff[u]);
            asm volatile("s_waitcnt vmcnt(8)" ::: "memory"); // current tile's 8 loads done
        } else {
            asm volatile("s_waitcnt vmcnt(0)" ::: "memory");
        }
        __builtin_amdgcn_s_barrier();          // all waves' loads for 'cur' are in LDS
        __builtin_amdgcn_sched_barrier(0);     // keep ds_reads below the barrier
        bf16x8 av[4][2], bv[4][2];
#pragma unroll
        for (int f = 0; f < 4; ++f)
#pragma unroll
            for (int kk = 0; kk < 2; ++kk) {
                av[f][kk] = *(const bf16x8*)&lA[cur][offA[f][kk]];
                bv[f][kk] = *(const bf16x8*)&lB[cur][offB[f][kk]];
            }
#pragma unroll
        for (int kk = 0; kk < 2; ++kk)
#pragma unroll
            for (int i = 0; i < 4; ++i)
#pragma unroll
                for (int j = 0; j < 4; ++j)
                    acc[i][j] = __builtin_amdgcn_mfma_f32_16x16x32_bf16(av[i][kk], bv[j][kk], acc[i][j], 0, 0, 0);
        __builtin_amdgcn_sched_barrier(0);     // keep reads/MFMA above the barrier
        __builtin_amdgcn_s_barrier();          // reads done before next overwrite
    }

    // epilogue: C/D layout col=lane&15, row=(lane>>4)*4+reg
    const int cl = ln & 15, rg = ln >> 4;
#pragma unroll
    for (int i = 0; i < 4; ++i) {
#pragma unroll
        for (int j = 0; j < 4; ++j) {
#pragma unroll
            for (int r = 0; r < 4; ++r) {
                int row = row0 + wr * 64 + i * 16 + rg * 4 + r;
                int col = col0 + wc * 64 + j * 16 + cl;
                float v = acc[i][j][r];
                if (bias) v += bias[col];
                if (dogelu) v = 0.5f * v * (1.0f + erff(v * 0.70710678118654752f));
                if (res) v += res[(size_t)(row & resMask) * N + col];
                if (Cf) Cf[(size_t)row * N + col] = v;
                if (Cb) Cb[(size_t)row * N + col] = f2bf(v);
            }
        }
    }
}

// ---------------- fused flash attention (bf16 MFMA) ----------------
__global__ __launch_bounds__(256) void fattn_k(
    const unsigned short* __restrict__ Qp, const unsigned short* __restrict__ Kp,
    const unsigned short* __restrict__ Vp, unsigned short* __restrict__ Op,
    int q_rstride, int kv_rstride, int o_rstride, int Sq, int Sk, int nh,
    float scale, const int* __restrict__ blk) {
    __shared__ unsigned short lK[64 * 64];
    __shared__ unsigned short lV[64 * 64];
    __shared__ unsigned short lP[4][16 * 64];
    const int t = threadIdx.x, wv = t >> 6, ln = t & 63;
    const int bh = blockIdx.x, b = bh / nh, hh = bh % nh;
    const int q0 = blockIdx.y * 64;
    const int tq = q0 >> 7;
    const int cl = ln & 15, rg = ln >> 4;

    bf16x8 qa[2];
    {
        const unsigned short* qrow = Qp + (size_t)(b * Sq + q0 + wv * 16 + cl) * q_rstride + hh * 64 + rg * 8;
        qa[0] = *(const bf16x8*)(qrow);
        qa[1] = *(const bf16x8*)(qrow + 32);
    }
    f32x4 oacc[4] = {};
    float mrow[4] = {-1e30f, -1e30f, -1e30f, -1e30f};
    float lrow[4] = {0.f, 0.f, 0.f, 0.f};

    int krr[2], kcc[2];
#pragma unroll
    for (int u = 0; u < 2; ++u) {
        int ch = u * 256 + t;
        krr[u] = ch >> 3;
        kcc[u] = ((ch & 7) ^ (krr[u] & 7)) << 3;
    }
    const int vk0 = (t >> 4) * 4, vd0 = (t & 15) * 4;

    for (int kc = 0; kc < Sk; kc += 64) {
        if (blk && blk[tq * 4 + (kc >> 7)]) continue;
        __syncthreads();
#pragma unroll
        for (int u = 0; u < 2; ++u)
            GLDS(Kp + (size_t)(b * Sk + kc + krr[u]) * kv_rstride + hh * 64 + kcc[u],
                 (char*)lK + ((u * 256 + wv * 64) << 4));
        {
            unsigned short a0[4], a1[4], a2[4], a3[4];
            const unsigned short* s0 = Vp + (size_t)(b * Sk + kc + vk0 + 0) * kv_rstride + hh * 64 + vd0;
            const unsigned short* s1 = Vp + (size_t)(b * Sk + kc + vk0 + 1) * kv_rstride + hh * 64 + vd0;
            const unsigned short* s2 = Vp + (size_t)(b * Sk + kc + vk0 + 2) * kv_rstride + hh * 64 + vd0;
            const unsigned short* s3 = Vp + (size_t)(b * Sk + kc + vk0 + 3) * kv_rstride + hh * 64 + vd0;
            *(uint2*)a0 = *(const uint2*)s0;
            *(uint2*)a1 = *(const uint2*)s1;
            *(uint2*)a2 = *(const uint2*)s2;
            *(uint2*)a3 = *(const uint2*)s3;
#pragma unroll
            for (int j = 0; j < 4; ++j) {
                int d = vd0 + j;
                int slot = (vk0 >> 3) ^ ((d + (d >> 3)) & 7);
                unsigned short pk[4] = {a0[j], a1[j], a2[j], a3[j]};
                *(uint2*)&lV[d * 64 + (slot << 3) + (vk0 & 7)] = *(uint2*)pk;
            }
        }
        __syncthreads();

        f32x4 sacc[4] = {};
#pragma unroll
        for (int kk = 0; kk < 2; ++kk)
#pragma unroll
            for (int f = 0; f < 4; ++f) {
                int rk = f * 16 + cl;
                bf16x8 kb = *(const bf16x8*)&lK[rk * 64 + (((kk * 4 + rg) ^ (rk & 7)) << 3)];
                sacc[f] = __builtin_amdgcn_mfma_f32_16x16x32_bf16(qa[kk], kb, sacc[f], 0, 0, 0);
            }
        float cm[4] = {-1e30f, -1e30f, -1e30f, -1e30f};
#pragma unroll
        for (int f = 0; f < 4; ++f)
#pragma unroll
            for (int r = 0; r < 4; ++r) {
                float v = sacc[f][r] * scale;
                sacc[f][r] = v;
                cm[r] = fmaxf(cm[r], v);
            }
#pragma unroll
        for (int o = 8; o; o >>= 1)
#pragma unroll
            for (int r = 0; r < 4; ++r) cm[r] = fmaxf(cm[r], __shfl_xor(cm[r], o));
        float corr[4], rsum[4];
#pragma unroll
        for (int r = 0; r < 4; ++r) {
            float nm = fmaxf(mrow[r], cm[r]);
            corr[r] = __expf(mrow[r] - nm);
            mrow[r] = nm;
            rsum[r] = 0.f;
        }
#pragma unroll
        for (int f = 0; f < 4; ++f)
#pragma unroll
            for (int r = 0; r < 4; ++r) {
                float p = __expf(sacc[f][r] - mrow[r]);
                sacc[f][r] = p;
                rsum[r] += p;
            }
#pragma unroll
        for (int o = 8; o; o >>= 1)
#pragma unroll
            for (int r = 0; r < 4; ++r) rsum[r] += __shfl_xor(rsum[r], o);
#pragma unroll
        for (int r = 0; r < 4; ++r) lrow[r] = lrow[r] * corr[r] + rsum[r];
#pragma unroll
        for (int f = 0; f < 4; ++f)
#pragma unroll
            for (int r = 0; r < 4; ++r) oacc[f][r] *= corr[r];
#pragma unroll
        for (int f = 0; f < 4; ++f)
#pragma unroll
            for (int r = 0; r < 4; ++r) {
                int q = rg * 4 + r, key = f * 16 + cl;
                lP[wv][q * 64 + (((key >> 3) ^ (q & 7)) << 3) + (key & 7)] = f2bf(sacc[f][r]);
            }
#pragma unroll
        for (int kk = 0; kk < 2; ++kk) {
            bf16x8 pa = *(const bf16x8*)&lP[wv][cl * 64 + (((kk * 4 + rg) ^ (cl & 7)) << 3)];
#pragma unroll
            for (int f = 0; f < 4; ++f) {
                int d = f * 16 + cl;
                bf16x8 vb = *(const bf16x8*)&lV[d * 64 + (((kk * 4 + rg) ^ ((d + (d >> 3)) & 7)) << 3)];
                oacc[f] = __builtin_amdgcn_mfma_f32_16x16x32_bf16(pa, vb, oacc[f], 0, 0, 0);
            }
        }
    }

    float inv[4];
#pragma unroll
    for (int r = 0; r < 4; ++r) inv[r] = 1.f / lrow[r];
#pragma unroll
    for (int f = 0; f < 4; ++f)
#pragma unroll
        for (int r = 0; r < 4; ++r) {
            int q = q0 + wv * 16 + rg * 4 + r;
            int d = f * 16 + cl;
            Op[(size_t)(b * Sq + q) * o_rstride + hh * 64 + d] = f2bf(oacc[f][r] * inv[r]);
        }
}

// ---------------- host ----------------
static inline void launch_gemm(hipStream_t stream, const unsigned short* A, const unsigned short* Bt,
                               const float* bias, const float* res, float* Cf, unsigned short* Cb,
                               int M, int N, int K, int dogelu, int resMask = -1, int Z = 1,
                               long long aBS = 0, long long bBS = 0, long long cBS = 0, long long biasBS = 0) {
    hipLaunchKernelGGL(mgemm_k, dim3(N / 128, M / 128, Z), dim3(256), 0, stream,
                       A, Bt, bias, res, Cf, Cb, N, K, dogelu, resMask, aBS, bBS, cBS, biasBS);
}

extern "C" void kernel_launch(void* const* d_in, const int* in_sizes, int n_in,
                              void* d_out, int out_size, void* d_ws, size_t ws_size,
                              hipStream_t stream) {
    (void)in_sizes; (void)n_in; (void)out_size; (void)ws_size;
    const float* x          = (const float*)d_in[0];
    const float* mask_rand  = (const float*)d_in[1];
    const float* conv_w     = (const float*)d_in[2];
    const float* conv_b     = (const float*)d_in[3];
    const float* pos_emb    = (const float*)d_in[4];
    const float* enc_ln1_s  = (const float*)d_in[5];
    const float* enc_ln1_b  = (const float*)d_in[6];
    const float* enc_qkv_w  = (const float*)d_in[7];
    const float* enc_proj_w = (const float*)d_in[8];
    const float* enc_proj_b = (const float*)d_in[9];
    const float* enc_ln2_s  = (const float*)d_in[10];
    const float* enc_ln2_b  = (const float*)d_in[11];
    const float* enc_mlp_w1 = (const float*)d_in[12];
    const float* enc_mlp_b1 = (const float*)d_in[13];
    const float* enc_mlp_w2 = (const float*)d_in[14];
    const float* enc_mlp_b2 = (const float*)d_in[15];
    const float* e2d_w      = (const float*)d_in[16];
    const float* e2d_b      = (const float*)d_in[17];
    const float* dec_query  = (const float*)d_in[18];
    const float* dec_ln1_s  = (const float*)d_in[19];
    const float* dec_ln1_b  = (const float*)d_in[20];
    const float* dec_qkv_w  = (const float*)d_in[21];
    const float* dec_qkv_b  = (const float*)d_in[22];
    const float* dec_out_w  = (const float*)d_in[23];
    const float* dec_out_b  = (const float*)d_in[24];
    const float* dec_ln2_s  = (const float*)d_in[25];
    const float* dec_ln2_b  = (const float*)d_in[26];
    const float* dec_mlp_w1 = (const float*)d_in[27];
    const float* dec_mlp_b1 = (const float*)d_in[28];
    const float* dec_mlp_w2 = (const float*)d_in[29];
    const float* dec_mlp_b2 = (const float*)d_in[30];
    const float* head_ln_s  = (const float*)d_in[31];
    const float* head_ln_b  = (const float*)d_in[32];
    const float* head_w     = (const float*)d_in[33];
    const float* head_b     = (const float*)d_in[34];
    float* outp = (float*)d_out;

    // ---- workspace layout (float units) ----
    float* w = (float*)d_ws;
    size_t off = 0;
    int* blockedp = (int*)w; off += 128;
    float* h_buf = w + off; off += (size_t)4096 * 768;
    unsigned short* y_bf = (unsigned short*)(w + off); off += (size_t)4096 * 768 / 2;
    unsigned short* qkv_bf = (unsigned short*)(w + off); off += (size_t)4096 * 2304 / 2;
    unsigned short* mlp_bf = (unsigned short*)(w + off); off += (size_t)4096 * 3072 / 2;
    unsigned short* mem_bf = (unsigned short*)(w + off); off += (size_t)4096 * 512 / 2;
    float* dq_buf = w + off; off += (size_t)1024 * 512;
    unsigned short* R = (unsigned short*)(w + off); off += (size_t)16777216 / 2;  // 33.5 MB region
    unsigned short* decQkvT = (unsigned short*)(w + off); off += (size_t)12 * 262144 / 2;
    unsigned short* decOutT = (unsigned short*)(w + off); off += (size_t)4 * 262144 / 2;
    unsigned short* decMlp1T = (unsigned short*)(w + off); off += (size_t)4 * 1048576 / 2;
    unsigned short* decMlp2T = (unsigned short*)(w + off); off += (size_t)4 * 1048576 / 2;
    unsigned short* e2dT = (unsigned short*)(w + off); off += (size_t)393216 / 2;
    unsigned short* headT = (unsigned short*)(w + off); off += (size_t)393216 / 2;

    // region R phases: convW (patchify) -> enc weight slot (encoder) -> K/V all layers (decoder)
    unsigned short* convW_bf = R;
    unsigned short* wqkvT = R;                          // 2304*768
    unsigned short* wprojT = R + (size_t)1769472;       // 768*768
    unsigned short* wmlp1T = R + (size_t)2359296;       // 3072*768
    unsigned short* wmlp2T = R + (size_t)4718592;       // 768*3072
    unsigned short* KdAll = R;                          // 4 * 4096*512
    unsigned short* VdAll = R + (size_t)8388608;

    unsigned short* xf_bf = mlp_bf;
    const float* fnull = nullptr;
    float* f32null = nullptr;
    unsigned short* bfnull = nullptr;
    const float scale = 0.125f;

    // ---- upfront prep ----
    hipLaunchKernelGGL(mask_k, dim3(1), dim3(128), 0, stream, mask_rand, blockedp);
    hipLaunchKernelGGL(wtrans_k, dim3(16, 16, 12), dim3(256), 0, stream, dec_qkv_w, decQkvT, 512, 512);
    hipLaunchKernelGGL(wtrans_k, dim3(16, 16, 4), dim3(256), 0, stream, dec_out_w, decOutT, 512, 512);
    hipLaunchKernelGGL(wtrans_k, dim3(64, 16, 4), dim3(256), 0, stream, dec_mlp_w1, decMlp1T, 512, 2048);
    hipLaunchKernelGGL(wtrans_k, dim3(16, 64, 4), dim3(256), 0, stream, dec_mlp_w2, decMlp2T, 2048, 512);
    hipLaunchKernelGGL(wtrans_k, dim3(16, 24, 1), dim3(256), 0, stream, e2d_w, e2dT, 768, 512);
    hipLaunchKernelGGL(wtrans_k, dim3(24, 16, 1), dim3(256), 0, stream, head_w, headT, 512, 768);
    hipLaunchKernelGGL(cast_k, dim3((768 * 3072 / 4 + 255) / 256), dim3(256), 0, stream,
                       conv_w, convW_bf, 768 * 3072 / 4);
    hipLaunchKernelGGL(gather_k, dim3(12288), dim3(256), 0, stream, x, xf_bf);
    // patchify GEMM + bias + pos_emb (res row & 511)
    launch_gemm(stream, xf_bf, convW_bf, conv_b, pos_emb, h_buf, bfnull, 4096, 768, 3072, 0, 511);

    // -------- encoder --------
    for (int l = 0; l < L_; ++l) {
        const int* blk = blockedp + l * 16;
        hipLaunchKernelGGL(ln_k, dim3(4096), dim3(256), 0, stream,
                           h_buf, y_bf, enc_ln1_s + l * 768, enc_ln1_b + l * 768, 768);
        hipLaunchKernelGGL(wtransenc_k, dim3(6912), dim3(256), 0, stream,
                           enc_qkv_w + (size_t)l * 768 * 2304, enc_proj_w + (size_t)l * 768 * 768,
                           enc_mlp_w1 + (size_t)l * 768 * 3072, enc_mlp_w2 + (size_t)l * 3072 * 768,
                           wqkvT, wprojT, wmlp1T, wmlp2T);
        launch_gemm(stream, y_bf, wqkvT, fnull, fnull, f32null, qkv_bf, 4096, 2304, 768, 0);
        hipLaunchKernelGGL(fattn_k, dim3(B_ * NH_, S_ / 64), dim3(256), 0, stream,
                           qkv_bf, qkv_bf + 768, qkv_bf + 1536, y_bf,
                           2304, 2304, 768, S_, S_, NH_, scale, blk);
        launch_gemm(stream, y_bf, wprojT, enc_proj_b + l * 768, h_buf, h_buf, bfnull, 4096, 768, 768, 0);
        hipLaunchKernelGGL(ln_k, dim3(4096), dim3(256), 0, stream,
                           h_buf, y_bf, enc_ln2_s + l * 768, enc_ln2_b + l * 768, 768);
        launch_gemm(stream, y_bf, wmlp1T, enc_mlp_b1 + l * 3072, fnull, f32null, mlp_bf, 4096, 3072, 768, 1);
        launch_gemm(stream, mlp_bf, wmlp2T, enc_mlp_b2 + l * 768, h_buf, h_buf, bfnull, 4096, 768, 3072, 0);
    }

    // -------- enc2dec --------
    hipLaunchKernelGGL(cast_k, dim3((4096 * 768 / 4 + 255) / 256), dim3(256), 0, stream,
                       h_buf, y_bf, 4096 * 768 / 4);
    launch_gemm(stream, y_bf, e2dT, e2d_b, fnull, f32null, mem_bf, 4096, 512, 768, 0);
    hipLaunchKernelGGL(dqinit_k, dim3(512), dim3(256), 0, stream, dq_buf, dec_query);
    // all-layer K and V (grouped GEMMs over z = layer)
    launch_gemm(stream, mem_bf, decQkvT + (size_t)262144, dec_qkv_b + 512, fnull, f32null, KdAll,
                4096, 512, 512, 0, -1, 4, 0, 3LL * 262144, 4096LL * 512, 3LL * 512);
    launch_gemm(stream, mem_bf, decQkvT + (size_t)2 * 262144, dec_qkv_b + 2 * 512, fnull, f32null, VdAll,
                4096, 512, 512, 0, -1, 4, 0, 3LL * 262144, 4096LL * 512, 3LL * 512);

    // -------- decoder --------
    unsigned short* Qd = qkv_bf;
    for (int l = 0; l < LD_; ++l) {
        unsigned short* Kd = KdAll + (size_t)l * 4096 * 512;
        unsigned short* Vd = VdAll + (size_t)l * 4096 * 512;
        hipLaunchKernelGGL(ln_k, dim3(1024), dim3(256), 0, stream,
                           dq_buf, y_bf, dec_ln1_s + l * 512, dec_ln1_b + l * 512, 512);
        launch_gemm(stream, y_bf, decQkvT + (size_t)(l * 3) * 262144, dec_qkv_b + (l * 3) * 512,
                    fnull, f32null, Qd, 1024, 512, 512, 0);
        hipLaunchKernelGGL(fattn_k, dim3(B_ * NHD_, P_ / 64), dim3(256), 0, stream,
                           Qd, Kd, Vd, y_bf, 512, 512, 512, P_, S_, NHD_, scale, (const int*)nullptr);
        launch_gemm(stream, y_bf, decOutT + (size_t)l * 262144, dec_out_b + l * 512,
                    dq_buf, dq_buf, bfnull, 1024, 512, 512, 0);
        hipLaunchKernelGGL(ln_k, dim3(1024), dim3(256), 0, stream,
                           dq_buf, y_bf, dec_ln2_s + l * 512, dec_ln2_b + l * 512, 512);
        launch_gemm(stream, y_bf, decMlp1T + (size_t)l * 1048576, dec_mlp_b1 + l * 2048,
                    fnull, f32null, mlp_bf, 1024, 2048, 512, 1);
        launch_gemm(stream, mlp_bf, decMlp2T + (size_t)l * 1048576, dec_mlp_b2 + l * 512,
                    dq_buf, dq_buf, bfnull, 1024, 512, 2048, 0);
    }

    // -------- head --------
    hipLaunchKernelGGL(ln_k, dim3(1024), dim3(256), 0, stream,
                       dq_buf, y_bf, head_ln_s, head_ln_b, 512);
    launch_gemm(stream, y_bf, headT, head_b, fnull, outp, bfnull, 1024, 768, 512, 0);
}

// Round 5
// 2385.703 us; speedup vs baseline: 7.3471x; 1.3015x over previous
//
#include <hip/hip_runtime.h>
#include <math.h>

// ---------------- dims ----------------
#define B_ 8
#define T_ 4
#define C_ 12
#define H_ 128
#define W_ 256
#define P_ 128
#define S_ 512
#define D_ 768
#define NH_ 12
#define HD_ 64
#define L_ 8
#define MLP_ 3072
#define DD_ 512
#define NHD_ 8
#define LD_ 4
#define MLPD_ 2048
#define OUT_ 768

typedef __bf16 bf16x8 __attribute__((ext_vector_type(8)));
typedef float f32x4 __attribute__((ext_vector_type(4)));

static __device__ __forceinline__ unsigned short f2bf(float f) {
    unsigned int u = __float_as_uint(f);
    unsigned int r = (u + 0x7fffu + ((u >> 16) & 1u)) >> 16;
    return (unsigned short)r;
}

#define GLDS(gp, lp) __builtin_amdgcn_global_load_lds( \
    (const __attribute__((address_space(1))) void*)(gp), \
    (__attribute__((address_space(3))) void*)(lp), 16, 0, 0)

// ---------------- small utility kernels ----------------

__global__ void mask_k(const float* __restrict__ mr, int* __restrict__ blocked) {
    int i = threadIdx.x; // 128 = L*T*T
    if (i < L_ * T_ * T_) {
        int tk = i & 3, tq = (i >> 2) & 3;
        blocked[i] = (mr[i] < 0.8f && tk > tq) ? 1 : 0;
    }
}

// batched transpose + cast: in (batch, Kd, Nd) fp32 -> out (batch, Nd, Kd) bf16
__global__ __launch_bounds__(256) void wtrans_k(const float* __restrict__ in, unsigned short* __restrict__ out,
                                                int Kd, int Nd) {
    __shared__ float tile[32][33];
    int n0 = blockIdx.x * 32, k0 = blockIdx.y * 32;
    size_t boff = (size_t)blockIdx.z * Kd * Nd;
    const float* src = in + boff;
    unsigned short* dst = out + boff;
    int tx = threadIdx.x & 31, ty = threadIdx.x >> 5; // 32 x 8
#pragma unroll
    for (int i = 0; i < 32; i += 8)
        tile[ty + i][tx] = src[(size_t)(k0 + ty + i) * Nd + n0 + tx];
    __syncthreads();
#pragma unroll
    for (int i = 0; i < 32; i += 8)
        dst[(size_t)(n0 + ty + i) * Kd + k0 + tx] = f2bf(tile[tx][ty + i]);
}

// one encoder layer: transpose all 4 weights in one launch (6912 tile-blocks)
__global__ __launch_bounds__(256) void wtransenc_k(const float* __restrict__ s0, const float* __restrict__ s1,
                                                   const float* __restrict__ s2, const float* __restrict__ s3,
                                                   unsigned short* __restrict__ d0, unsigned short* __restrict__ d1,
                                                   unsigned short* __restrict__ d2, unsigned short* __restrict__ d3) {
    __shared__ float tile[32][33];
    int bid = blockIdx.x;
    const float* src; unsigned short* dst; int Kd, Nd, tt;
    if (bid < 1728)      { src = s0; dst = d0; Kd = 768;  Nd = 2304; tt = bid; }
    else if (bid < 2304) { src = s1; dst = d1; Kd = 768;  Nd = 768;  tt = bid - 1728; }
    else if (bid < 4608) { src = s2; dst = d2; Kd = 768;  Nd = 3072; tt = bid - 2304; }
    else                 { src = s3; dst = d3; Kd = 3072; Nd = 768;  tt = bid - 4608; }
    int nT = Nd >> 5;
    int n0 = (tt % nT) * 32, k0 = (tt / nT) * 32;
    int tx = threadIdx.x & 31, ty = threadIdx.x >> 5;
#pragma unroll
    for (int i = 0; i < 32; i += 8)
        tile[ty + i][tx] = src[(size_t)(k0 + ty + i) * Nd + n0 + tx];
    __syncthreads();
#pragma unroll
    for (int i = 0; i < 32; i += 8)
        dst[(size_t)(n0 + ty + i) * Kd + k0 + tx] = f2bf(tile[tx][ty + i]);
}

// xf[bt, p, c*256+ph*16+pw] = x[bt, c, hp*16+ph, wp*16+pw]  (bf16 out)
__global__ void gather_k(const float* __restrict__ x, unsigned short* __restrict__ xf) {
    size_t i4 = ((size_t)blockIdx.x * 256 + threadIdx.x) * 4;
    if (i4 >= (size_t)4096 * 3072) return;
    int row = (int)(i4 / 3072), col = (int)(i4 % 3072);
    int bt = row >> 7, p = row & 127;
    int hp = p >> 4, wp = p & 15;
    int c = col >> 8, rem = col & 255;
    int ph = rem >> 4, pw0 = rem & 15;
    const float* src = x + (((size_t)(bt * C_ + c) * H_ + hp * 16 + ph) * W_ + wp * 16 + pw0);
    float4 v = *(const float4*)src;
    uint2 o;
    o.x = (unsigned)f2bf(v.x) | ((unsigned)f2bf(v.y) << 16);
    o.y = (unsigned)f2bf(v.z) | ((unsigned)f2bf(v.w) << 16);
    *(uint2*)(xf + i4) = o;
}

// linear cast fp32 -> bf16, n multiple of 4
__global__ void cast_k(const float* __restrict__ in, unsigned short* __restrict__ out, int n4) {
    int i = blockIdx.x * 256 + threadIdx.x;
    if (i >= n4) return;
    float4 v = *(const float4*)(in + (size_t)i * 4);
    uint2 o;
    o.x = (unsigned)f2bf(v.x) | ((unsigned)f2bf(v.y) << 16);
    o.y = (unsigned)f2bf(v.z) | ((unsigned)f2bf(v.w) << 16);
    *(uint2*)(out + (size_t)i * 4) = o;
}

// dq[(b*128+p)*512+c] = dec_query[p*512+c]
__global__ void dqinit_k(float* __restrict__ dq, const float* __restrict__ q0) {
    size_t i4 = ((size_t)blockIdx.x * 256 + threadIdx.x) * 4;
    if (i4 >= (size_t)1024 * 512) return;
    int row = (int)(i4 / 512), col = (int)(i4 % 512);
    int p = row & 127;
    *(float4*)(dq + i4) = *(const float4*)(q0 + (size_t)p * 512 + col);
}

// ---------------- layernorm: fp32 in -> bf16 out ----------------
__global__ __launch_bounds__(256) void ln_k(const float* __restrict__ X, unsigned short* __restrict__ Y,
                                            const float* __restrict__ sc, const float* __restrict__ bi,
                                            int cols) {
    int row = blockIdx.x;
    int t = threadIdx.x;
    const float* x = X + (size_t)row * cols;
    float s = 0.f, sq = 0.f;
    for (int c = t; c < cols; c += 256) { float v = x[c]; s += v; sq += v * v; }
    for (int o = 32; o; o >>= 1) { s += __shfl_xor(s, o); sq += __shfl_xor(sq, o); }
    __shared__ float rs[4], rq[4];
    if ((t & 63) == 0) { rs[t >> 6] = s; rq[t >> 6] = sq; }
    __syncthreads();
    s = rs[0] + rs[1] + rs[2] + rs[3];
    sq = rq[0] + rq[1] + rq[2] + rq[3];
    float mean = s / cols;
    float var = sq / cols - mean * mean;
    float inv = rsqrtf(var + 1e-5f);
    unsigned short* y = Y + (size_t)row * cols;
    for (int c = t; c < cols; c += 256) {
        float v = (x[c] - mean) * inv;
        y[c] = f2bf(v * sc[c] + bi[c]);
    }
}

// ---------------- bf16 MFMA GEMM: double-buffered, counted vmcnt ----------------
// A: MxKstride bf16 row-major (compute over Klen cols). Bt: NxKstride bf16 (= B^T).
// Tile 128x128, BK=64, 4 waves. blockIdx.z: grouped batch OR K-split (via aBS/bBS/cBS).
__global__ __launch_bounds__(256, 2) void mgemm_k(const unsigned short* __restrict__ A,
                                                  const unsigned short* __restrict__ Bt,
                                                  const float* __restrict__ bias,
                                                  const float* __restrict__ res,
                                                  float* Cf, unsigned short* Cb,
                                                  int N, int Kstride, int Klen, int dogelu, int resMask,
                                                  long long aBS, long long bBS, long long cBS, long long biasBS) {
    __shared__ unsigned short lA[2][128 * 64];
    __shared__ unsigned short lB[2][128 * 64];
    const int t = threadIdx.x, w = t >> 6, ln = t & 63;

    const int z = blockIdx.z;
    A += (size_t)z * aBS;
    Bt += (size_t)z * bBS;
    if (bias) bias += (size_t)z * biasBS;
    if (Cf) Cf += (size_t)z * cBS;
    if (Cb) Cb += (size_t)z * cBS;

    // bijective XCD swizzle (m204)
    int nwg = gridDim.x * gridDim.y;
    int orig = blockIdx.y * gridDim.x + blockIdx.x;
    int qq = nwg >> 3, rr = nwg & 7;
    int xcd = orig & 7, lid = orig >> 3;
    int swz = (xcd < rr) ? (xcd * (qq + 1) + lid) : (rr * (qq + 1) + (xcd - rr) * qq + lid);
    const int row0 = (swz / gridDim.x) * 128, col0 = (swz % gridDim.x) * 128;
    const int wr = w >> 1, wc = w & 1;

    f32x4 acc[4][4] = {};

    // staging sources (inverse-swizzled global addresses)
    const unsigned short* gA[4];
    const unsigned short* gB[4];
    int ldsOff[4];
#pragma unroll
    for (int u = 0; u < 4; ++u) {
        int ch = u * 256 + w * 64 + ln;
        int r = ch >> 3, c = ch & 7;
        int sc_ = ((c ^ (r & 7)) << 3);
        gA[u] = A + (size_t)(row0 + r) * Kstride + sc_;
        gB[u] = Bt + (size_t)(col0 + r) * Kstride + sc_;
        ldsOff[u] = (u * 256 + w * 64) << 4; // wave-uniform byte base
    }
    int offA[4][2], offB[4][2];
#pragma unroll
    for (int f = 0; f < 4; ++f)
#pragma unroll
        for (int kk = 0; kk < 2; ++kk) {
            int ra = wr * 64 + f * 16 + (ln & 15);
            offA[f][kk] = ra * 64 + (((kk * 4 + (ln >> 4)) ^ (ra & 7)) << 3);
            int rb = wc * 64 + f * 16 + (ln & 15);
            offB[f][kk] = rb * 64 + (((kk * 4 + (ln >> 4)) ^ (rb & 7)) << 3);
        }

    const int nt = Klen >> 6;
    // prologue: stage tile 0 into buffer 0
#pragma unroll
    for (int u = 0; u < 4; ++u) GLDS(gA[u], (char*)&lA[0][0] + ldsOff[u]);
#pragma unroll
    for (int u = 0; u < 4; ++u) GLDS(gB[u], (char*)&lB[0][0] + ldsOff[u]);

    for (int tt = 0; tt < nt; ++tt) {
        const int cur = tt & 1;
        if (tt + 1 < nt) {
            const int koff = (tt + 1) << 6;
#pragma unroll
            for (int u = 0; u < 4; ++u) GLDS(gA[u] + koff, (char*)&lA[cur ^ 1][0] + ldsOff[u]);
#pragma unroll
            for (int u = 0; u < 4; ++u) GLDS(gB[u] + koff, (char*)&lB[cur ^ 1][0] + ldsOff[u]);
            asm volatile("s_waitcnt vmcnt(8)" ::: "memory");
        } else {
            asm volatile("s_waitcnt vmcnt(0)" ::: "memory");
        }
        __builtin_amdgcn_s_barrier();
        __builtin_amdgcn_sched_barrier(0);
        bf16x8 av[4][2], bv[4][2];
#pragma unroll
        for (int f = 0; f < 4; ++f)
#pragma unroll
            for (int kk = 0; kk < 2; ++kk) {
                av[f][kk] = *(const bf16x8*)&lA[cur][offA[f][kk]];
                bv[f][kk] = *(const bf16x8*)&lB[cur][offB[f][kk]];
            }
#pragma unroll
        for (int kk = 0; kk < 2; ++kk)
#pragma unroll
            for (int i = 0; i < 4; ++i)
#pragma unroll
                for (int j = 0; j < 4; ++j)
                    acc[i][j] = __builtin_amdgcn_mfma_f32_16x16x32_bf16(av[i][kk], bv[j][kk], acc[i][j], 0, 0, 0);
        __builtin_amdgcn_sched_barrier(0);
        __builtin_amdgcn_s_barrier();
    }

    // epilogue: C/D layout col=lane&15, row=(lane>>4)*4+reg
    const int cl = ln & 15, rg = ln >> 4;
#pragma unroll
    for (int i = 0; i < 4; ++i) {
#pragma unroll
        for (int j = 0; j < 4; ++j) {
#pragma unroll
            for (int r = 0; r < 4; ++r) {
                int row = row0 + wr * 64 + i * 16 + rg * 4 + r;
                int col = col0 + wc * 64 + j * 16 + cl;
                float v = acc[i][j][r];
                if (bias) v += bias[col];
                if (dogelu) v = 0.5f * v * (1.0f + erff(v * 0.70710678118654752f));
                if (res) v += res[(size_t)(row & resMask) * N + col];
                if (Cf) Cf[(size_t)row * N + col] = v;
                if (Cb) Cb[(size_t)row * N + col] = f2bf(v);
            }
        }
    }
}

// ---------------- split-K reduce + epilogue ----------------
// sums S partials (stride pstride), applies bias/gelu/res, writes fp32 and/or bf16
__global__ __launch_bounds__(256) void redep_k(const float* __restrict__ part, int S, long long pstride,
                                               const float* __restrict__ bias, const float* __restrict__ res,
                                               float* __restrict__ Cf, unsigned short* __restrict__ Cb,
                                               int N, int dogelu, int resMask) {
    size_t i4 = ((size_t)blockIdx.x * 256 + threadIdx.x) * 4;
    int row = (int)(i4 / N), col = (int)(i4 % N);
    float4 acc = *(const float4*)(part + i4);
    for (int s = 1; s < S; ++s) {
        float4 p = *(const float4*)(part + (size_t)s * pstride + i4);
        acc.x += p.x; acc.y += p.y; acc.z += p.z; acc.w += p.w;
    }
    if (bias) {
        float4 bv = *(const float4*)(bias + col);
        acc.x += bv.x; acc.y += bv.y; acc.z += bv.z; acc.w += bv.w;
    }
    if (dogelu) {
        acc.x = 0.5f * acc.x * (1.0f + erff(acc.x * 0.70710678118654752f));
        acc.y = 0.5f * acc.y * (1.0f + erff(acc.y * 0.70710678118654752f));
        acc.z = 0.5f * acc.z * (1.0f + erff(acc.z * 0.70710678118654752f));
        acc.w = 0.5f * acc.w * (1.0f + erff(acc.w * 0.70710678118654752f));
    }
    if (res) {
        float4 rv = *(const float4*)(res + (size_t)(row & resMask) * N + col);
        acc.x += rv.x; acc.y += rv.y; acc.z += rv.z; acc.w += rv.w;
    }
    if (Cf) *(float4*)(Cf + i4) = acc;
    if (Cb) {
        uint2 o;
        o.x = (unsigned)f2bf(acc.x) | ((unsigned)f2bf(acc.y) << 16);
        o.y = (unsigned)f2bf(acc.z) | ((unsigned)f2bf(acc.w) << 16);
        *(uint2*)(Cb + i4) = o;
    }
}

// ---------------- fused flash attention (bf16 MFMA) ----------------
__global__ __launch_bounds__(256) void fattn_k(
    const unsigned short* __restrict__ Qp, const unsigned short* __restrict__ Kp,
    const unsigned short* __restrict__ Vp, unsigned short* __restrict__ Op,
    int q_rstride, int kv_rstride, int o_rstride, int Sq, int Sk, int nh,
    float scale, const int* __restrict__ blk) {
    __shared__ unsigned short lK[64 * 64];
    __shared__ unsigned short lV[64 * 64];
    __shared__ unsigned short lP[4][16 * 64];
    const int t = threadIdx.x, wv = t >> 6, ln = t & 63;
    const int bh = blockIdx.x, b = bh / nh, hh = bh % nh;
    const int q0 = blockIdx.y * 64;
    const int tq = q0 >> 7;
    const int cl = ln & 15, rg = ln >> 4;

    bf16x8 qa[2];
    {
        const unsigned short* qrow = Qp + (size_t)(b * Sq + q0 + wv * 16 + cl) * q_rstride + hh * 64 + rg * 8;
        qa[0] = *(const bf16x8*)(qrow);
        qa[1] = *(const bf16x8*)(qrow + 32);
    }
    f32x4 oacc[4] = {};
    float mrow[4] = {-1e30f, -1e30f, -1e30f, -1e30f};
    float lrow[4] = {0.f, 0.f, 0.f, 0.f};

    int krr[2], kcc[2];
#pragma unroll
    for (int u = 0; u < 2; ++u) {
        int ch = u * 256 + t;
        krr[u] = ch >> 3;
        kcc[u] = ((ch & 7) ^ (krr[u] & 7)) << 3;
    }
    const int vk0 = (t >> 4) * 4, vd0 = (t & 15) * 4;

    for (int kc = 0; kc < Sk; kc += 64) {
        if (blk && blk[tq * 4 + (kc >> 7)]) continue;
        __syncthreads();
#pragma unroll
        for (int u = 0; u < 2; ++u)
            GLDS(Kp + (size_t)(b * Sk + kc + krr[u]) * kv_rstride + hh * 64 + kcc[u],
                 (char*)lK + ((u * 256 + wv * 64) << 4));
        {
            unsigned short a0[4], a1[4], a2[4], a3[4];
            const unsigned short* s0 = Vp + (size_t)(b * Sk + kc + vk0 + 0) * kv_rstride + hh * 64 + vd0;
            const unsigned short* s1 = Vp + (size_t)(b * Sk + kc + vk0 + 1) * kv_rstride + hh * 64 + vd0;
            const unsigned short* s2 = Vp + (size_t)(b * Sk + kc + vk0 + 2) * kv_rstride + hh * 64 + vd0;
            const unsigned short* s3 = Vp + (size_t)(b * Sk + kc + vk0 + 3) * kv_rstride + hh * 64 + vd0;
            *(uint2*)a0 = *(const uint2*)s0;
            *(uint2*)a1 = *(const uint2*)s1;
            *(uint2*)a2 = *(const uint2*)s2;
            *(uint2*)a3 = *(const uint2*)s3;
#pragma unroll
            for (int j = 0; j < 4; ++j) {
                int d = vd0 + j;
                int slot = (vk0 >> 3) ^ ((d + (d >> 3)) & 7);
                unsigned short pk[4] = {a0[j], a1[j], a2[j], a3[j]};
                *(uint2*)&lV[d * 64 + (slot << 3) + (vk0 & 7)] = *(uint2*)pk;
            }
        }
        __syncthreads();

        f32x4 sacc[4] = {};
#pragma unroll
        for (int kk = 0; kk < 2; ++kk)
#pragma unroll
            for (int f = 0; f < 4; ++f) {
                int rk = f * 16 + cl;
                bf16x8 kb = *(const bf16x8*)&lK[rk * 64 + (((kk * 4 + rg) ^ (rk & 7)) << 3)];
                sacc[f] = __builtin_amdgcn_mfma_f32_16x16x32_bf16(qa[kk], kb, sacc[f], 0, 0, 0);
            }
        float cm[4] = {-1e30f, -1e30f, -1e30f, -1e30f};
#pragma unroll
        for (int f = 0; f < 4; ++f)
#pragma unroll
            for (int r = 0; r < 4; ++r) {
                float v = sacc[f][r] * scale;
                sacc[f][r] = v;
                cm[r] = fmaxf(cm[r], v);
            }
#pragma unroll
        for (int o = 8; o; o >>= 1)
#pragma unroll
            for (int r = 0; r < 4; ++r) cm[r] = fmaxf(cm[r], __shfl_xor(cm[r], o));
        float corr[4], rsum[4];
#pragma unroll
        for (int r = 0; r < 4; ++r) {
            float nm = fmaxf(mrow[r], cm[r]);
            corr[r] = __expf(mrow[r] - nm);
            mrow[r] = nm;
            rsum[r] = 0.f;
        }
#pragma unroll
        for (int f = 0; f < 4; ++f)
#pragma unroll
            for (int r = 0; r < 4; ++r) {
                float p = __expf(sacc[f][r] - mrow[r]);
                sacc[f][r] = p;
                rsum[r] += p;
            }
#pragma unroll
        for (int o = 8; o; o >>= 1)
#pragma unroll
            for (int r = 0; r < 4; ++r) rsum[r] += __shfl_xor(rsum[r], o);
#pragma unroll
        for (int r = 0; r < 4; ++r) lrow[r] = lrow[r] * corr[r] + rsum[r];
#pragma unroll
        for (int f = 0; f < 4; ++f)
#pragma unroll
            for (int r = 0; r < 4; ++r) oacc[f][r] *= corr[r];
#pragma unroll
        for (int f = 0; f < 4; ++f)
#pragma unroll
            for (int r = 0; r < 4; ++r) {
                int q = rg * 4 + r, key = f * 16 + cl;
                lP[wv][q * 64 + (((key >> 3) ^ (q & 7)) << 3) + (key & 7)] = f2bf(sacc[f][r]);
            }
#pragma unroll
        for (int kk = 0; kk < 2; ++kk) {
            bf16x8 pa = *(const bf16x8*)&lP[wv][cl * 64 + (((kk * 4 + rg) ^ (cl & 7)) << 3)];
#pragma unroll
            for (int f = 0; f < 4; ++f) {
                int d = f * 16 + cl;
                bf16x8 vb = *(const bf16x8*)&lV[d * 64 + (((kk * 4 + rg) ^ ((d + (d >> 3)) & 7)) << 3)];
                oacc[f] = __builtin_amdgcn_mfma_f32_16x16x32_bf16(pa, vb, oacc[f], 0, 0, 0);
            }
        }
    }

    float inv[4];
#pragma unroll
    for (int r = 0; r < 4; ++r) inv[r] = 1.f / lrow[r];
#pragma unroll
    for (int f = 0; f < 4; ++f)
#pragma unroll
        for (int r = 0; r < 4; ++r) {
            int q = q0 + wv * 16 + rg * 4 + r;
            int d = f * 16 + cl;
            Op[(size_t)(b * Sq + q) * o_rstride + hh * 64 + d] = f2bf(oacc[f][r] * inv[r]);
        }
}

// ---------------- host helpers ----------------
static inline void launch_gemm(hipStream_t stream, const unsigned short* A, const unsigned short* Bt,
                               const float* bias, const float* res, float* Cf, unsigned short* Cb,
                               int M, int N, int K, int dogelu, int resMask = -1, int Z = 1,
                               long long aBS = 0, long long bBS = 0, long long cBS = 0, long long biasBS = 0) {
    hipLaunchKernelGGL(mgemm_k, dim3(N / 128, M / 128, Z), dim3(256), 0, stream,
                       A, Bt, bias, res, Cf, Cb, N, K, K, dogelu, resMask, aBS, bBS, cBS, biasBS);
}

static inline void gemm_splitk(hipStream_t stream, const unsigned short* A, const unsigned short* Bt,
                               float* part, int M, int N, int K, int S,
                               const float* bias, const float* res, float* Cf, unsigned short* Cb,
                               int dogelu, int resMask = -1) {
    int Klen = K / S;
    hipLaunchKernelGGL(mgemm_k, dim3(N / 128, M / 128, S), dim3(256), 0, stream,
                       A, Bt, (const float*)nullptr, (const float*)nullptr, part, (unsigned short*)nullptr,
                       N, K, Klen, 0, -1, (long long)Klen, (long long)Klen, (long long)M * N, 0LL);
    hipLaunchKernelGGL(redep_k, dim3((unsigned)((size_t)M * N / 1024)), dim3(256), 0, stream,
                       part, S, (long long)M * N, bias, res, Cf, Cb, N, dogelu, resMask);
}

extern "C" void kernel_launch(void* const* d_in, const int* in_sizes, int n_in,
                              void* d_out, int out_size, void* d_ws, size_t ws_size,
                              hipStream_t stream) {
    (void)in_sizes; (void)n_in; (void)out_size; (void)ws_size;
    const float* x          = (const float*)d_in[0];
    const float* mask_rand  = (const float*)d_in[1];
    const float* conv_w     = (const float*)d_in[2];
    const float* conv_b     = (const float*)d_in[3];
    const float* pos_emb    = (const float*)d_in[4];
    const float* enc_ln1_s  = (const float*)d_in[5];
    const float* enc_ln1_b  = (const float*)d_in[6];
    const float* enc_qkv_w  = (const float*)d_in[7];
    const float* enc_proj_w = (const float*)d_in[8];
    const float* enc_proj_b = (const float*)d_in[9];
    const float* enc_ln2_s  = (const float*)d_in[10];
    const float* enc_ln2_b  = (const float*)d_in[11];
    const float* enc_mlp_w1 = (const float*)d_in[12];
    const float* enc_mlp_b1 = (const float*)d_in[13];
    const float* enc_mlp_w2 = (const float*)d_in[14];
    const float* enc_mlp_b2 = (const float*)d_in[15];
    const float* e2d_w      = (const float*)d_in[16];
    const float* e2d_b      = (const float*)d_in[17];
    const float* dec_query  = (const float*)d_in[18];
    const float* dec_ln1_s  = (const float*)d_in[19];
    const float* dec_ln1_b  = (const float*)d_in[20];
    const float* dec_qkv_w  = (const float*)d_in[21];
    const float* dec_qkv_b  = (const float*)d_in[22];
    const float* dec_out_w  = (const float*)d_in[23];
    const float* dec_out_b  = (const float*)d_in[24];
    const float* dec_ln2_s  = (const float*)d_in[25];
    const float* dec_ln2_b  = (const float*)d_in[26];
    const float* dec_mlp_w1 = (const float*)d_in[27];
    const float* dec_mlp_b1 = (const float*)d_in[28];
    const float* dec_mlp_w2 = (const float*)d_in[29];
    const float* dec_mlp_b2 = (const float*)d_in[30];
    const float* head_ln_s  = (const float*)d_in[31];
    const float* head_ln_b  = (const float*)d_in[32];
    const float* head_w     = (const float*)d_in[33];
    const float* head_b     = (const float*)d_in[34];
    float* outp = (float*)d_out;

    // ---- workspace layout (float units) ----
    float* w = (float*)d_ws;
    size_t off = 0;
    int* blockedp = (int*)w; off += 128;
    float* h_buf = w + off; off += (size_t)4096 * 768;
    unsigned short* y_bf = (unsigned short*)(w + off); off += (size_t)4096 * 768 / 2;
    unsigned short* qkv_bf = (unsigned short*)(w + off); off += (size_t)4096 * 2304 / 2;
    unsigned short* mlp_bf = (unsigned short*)(w + off); off += (size_t)4096 * 3072 / 2;
    unsigned short* mem_bf = (unsigned short*)(w + off); off += (size_t)4096 * 512 / 2;
    float* dq_buf = w + off; off += (size_t)1024 * 512;
    unsigned short* R = (unsigned short*)(w + off); off += (size_t)16777216 / 2;  // 33.5 MB region
    unsigned short* decQkvT = (unsigned short*)(w + off); off += (size_t)12 * 262144 / 2;
    unsigned short* decOutT = (unsigned short*)(w + off); off += (size_t)4 * 262144 / 2;
    unsigned short* decMlp1T = (unsigned short*)(w + off); off += (size_t)4 * 1048576 / 2;
    unsigned short* decMlp2T = (unsigned short*)(w + off); off += (size_t)4 * 1048576 / 2;
    unsigned short* e2dT = (unsigned short*)(w + off); off += (size_t)393216 / 2;
    unsigned short* headT = (unsigned short*)(w + off); off += (size_t)393216 / 2;
    float* part_buf = w + off; off += (size_t)4 * 4096 * 768;  // split-K partials (50 MB max)

    // region R phases: convW (patchify) -> enc weight slot (encoder) -> K/V all layers (decoder)
    unsigned short* convW_bf = R;
    unsigned short* wqkvT = R;                          // 2304*768
    unsigned short* wprojT = R + (size_t)1769472;       // 768*768
    unsigned short* wmlp1T = R + (size_t)2359296;       // 3072*768
    unsigned short* wmlp2T = R + (size_t)4718592;       // 768*3072
    unsigned short* KdAll = R;                          // 4 * 4096*512
    unsigned short* VdAll = R + (size_t)8388608;

    unsigned short* xf_bf = mlp_bf;
    const float* fnull = nullptr;
    float* f32null = nullptr;
    unsigned short* bfnull = nullptr;
    const float scale = 0.125f;

    // ---- upfront prep ----
    hipLaunchKernelGGL(mask_k, dim3(1), dim3(128), 0, stream, mask_rand, blockedp);
    hipLaunchKernelGGL(wtrans_k, dim3(16, 16, 12), dim3(256), 0, stream, dec_qkv_w, decQkvT, 512, 512);
    hipLaunchKernelGGL(wtrans_k, dim3(16, 16, 4), dim3(256), 0, stream, dec_out_w, decOutT, 512, 512);
    hipLaunchKernelGGL(wtrans_k, dim3(64, 16, 4), dim3(256), 0, stream, dec_mlp_w1, decMlp1T, 512, 2048);
    hipLaunchKernelGGL(wtrans_k, dim3(16, 64, 4), dim3(256), 0, stream, dec_mlp_w2, decMlp2T, 2048, 512);
    hipLaunchKernelGGL(wtrans_k, dim3(16, 24, 1), dim3(256), 0, stream, e2d_w, e2dT, 768, 512);
    hipLaunchKernelGGL(wtrans_k, dim3(24, 16, 1), dim3(256), 0, stream, head_w, headT, 512, 768);
    hipLaunchKernelGGL(cast_k, dim3((768 * 3072 / 4 + 255) / 256), dim3(256), 0, stream,
                       conv_w, convW_bf, 768 * 3072 / 4);
    hipLaunchKernelGGL(gather_k, dim3(12288), dim3(256), 0, stream, x, xf_bf);
    // patchify GEMM (split-K 4) + bias + pos_emb (res row & 511)
    gemm_splitk(stream, xf_bf, convW_bf, part_buf, 4096, 768, 3072, 4,
                conv_b, pos_emb, h_buf, bfnull, 0, 511);

    // -------- encoder --------
    for (int l = 0; l < L_; ++l) {
        const int* blk = blockedp + l * 16;
        hipLaunchKernelGGL(ln_k, dim3(4096), dim3(256), 0, stream,
                           h_buf, y_bf, enc_ln1_s + l * 768, enc_ln1_b + l * 768, 768);
        hipLaunchKernelGGL(wtransenc_k, dim3(6912), dim3(256), 0, stream,
                           enc_qkv_w + (size_t)l * 768 * 2304, enc_proj_w + (size_t)l * 768 * 768,
                           enc_mlp_w1 + (size_t)l * 768 * 3072, enc_mlp_w2 + (size_t)l * 3072 * 768,
                           wqkvT, wprojT, wmlp1T, wmlp2T);
        launch_gemm(stream, y_bf, wqkvT, fnull, fnull, f32null, qkv_bf, 4096, 2304, 768, 0);
        hipLaunchKernelGGL(fattn_k, dim3(B_ * NH_, S_ / 64), dim3(256), 0, stream,
                           qkv_bf, qkv_bf + 768, qkv_bf + 1536, y_bf,
                           2304, 2304, 768, S_, S_, NH_, scale, blk);
        // proj: split-K 2, res = h
        gemm_splitk(stream, y_bf, wprojT, part_buf, 4096, 768, 768, 2,
                    enc_proj_b + l * 768, h_buf, h_buf, bfnull, 0);
        hipLaunchKernelGGL(ln_k, dim3(4096), dim3(256), 0, stream,
                           h_buf, y_bf, enc_ln2_s + l * 768, enc_ln2_b + l * 768, 768);
        launch_gemm(stream, y_bf, wmlp1T, enc_mlp_b1 + l * 3072, fnull, f32null, mlp_bf, 4096, 3072, 768, 1);
        // mlp2: split-K 4, res = h; on last layer also emit bf16 for e2d
        gemm_splitk(stream, mlp_bf, wmlp2T, part_buf, 4096, 768, 3072, 4,
                    enc_mlp_b2 + l * 768, h_buf, h_buf, (l == L_ - 1) ? y_bf : bfnull, 0);
    }

    // -------- enc2dec --------
    gemm_splitk(stream, y_bf, e2dT, part_buf, 4096, 512, 768, 2,
                e2d_b, fnull, f32null, mem_bf, 0);
    hipLaunchKernelGGL(dqinit_k, dim3(512), dim3(256), 0, stream, dq_buf, dec_query);
    // all-layer K and V (grouped GEMMs over z = layer)
    launch_gemm(stream, mem_bf, decQkvT + (size_t)262144, dec_qkv_b + 512, fnull, f32null, KdAll,
                4096, 512, 512, 0, -1, 4, 0, 3LL * 262144, 4096LL * 512, 3LL * 512);
    launch_gemm(stream, mem_bf, decQkvT + (size_t)2 * 262144, dec_qkv_b + 2 * 512, fnull, f32null, VdAll,
                4096, 512, 512, 0, -1, 4, 0, 3LL * 262144, 4096LL * 512, 3LL * 512);

    // -------- decoder --------
    unsigned short* Qd = qkv_bf;
    for (int l = 0; l < LD_; ++l) {
        unsigned short* Kd = KdAll + (size_t)l * 4096 * 512;
        unsigned short* Vd = VdAll + (size_t)l * 4096 * 512;
        hipLaunchKernelGGL(ln_k, dim3(1024), dim3(256), 0, stream,
                           dq_buf, y_bf, dec_ln1_s + l * 512, dec_ln1_b + l * 512, 512);
        gemm_splitk(stream, y_bf, decQkvT + (size_t)(l * 3) * 262144, part_buf, 1024, 512, 512, 4,
                    dec_qkv_b + (l * 3) * 512, fnull, f32null, Qd, 0);
        hipLaunchKernelGGL(fattn_k, dim3(B_ * NHD_, P_ / 64), dim3(256), 0, stream,
                           Qd, Kd, Vd, y_bf, 512, 512, 512, P_, S_, NHD_, scale, (const int*)nullptr);
        gemm_splitk(stream, y_bf, decOutT + (size_t)l * 262144, part_buf, 1024, 512, 512, 4,
                    dec_out_b + l * 512, dq_buf, dq_buf, bfnull, 0);
        hipLaunchKernelGGL(ln_k, dim3(1024), dim3(256), 0, stream,
                           dq_buf, y_bf, dec_ln2_s + l * 512, dec_ln2_b + l * 512, 512);
        gemm_splitk(stream, y_bf, decMlp1T + (size_t)l * 1048576, part_buf, 1024, 2048, 512, 2,
                    dec_mlp_b1 + l * 2048, fnull, f32null, mlp_bf, 1);
        gemm_splitk(stream, mlp_bf, decMlp2T + (size_t)l * 1048576, part_buf, 1024, 512, 2048, 8,
                    dec_mlp_b2 + l * 512, dq_buf, dq_buf, bfnull, 0);
    }

    // -------- head --------
    hipLaunchKernelGGL(ln_k, dim3(1024), dim3(256), 0, stream,
                       dq_buf, y_bf, head_ln_s, head_ln_b, 512);
    gemm_splitk(stream, y_bf, headT, part_buf, 1024, 768, 512, 4,
                head_b, fnull, outp, bfnull, 0);
}